// Round 1
// baseline (733.155 us; speedup 1.0000x reference)
//
#include <hip/hip_runtime.h>
#include <stdint.h>

#define TPB 256
#define RPT 4
#define NL 4

typedef _Float16 half2v __attribute__((ext_vector_type(2)));

static __device__ __forceinline__ uint32_t packh2(float a, float b) {
  half2v h;
  h.x = (_Float16)a;
  h.y = (_Float16)b;
  return __builtin_bit_cast(uint32_t, h);
}
static __device__ __forceinline__ float2 unpackh2(uint32_t u) {
  half2v h = __builtin_bit_cast(half2v, u);
  return make_float2((float)h.x, (float)h.y);
}
static __device__ __forceinline__ float fdot2h(uint32_t a, uint32_t b, float c) {
#if __has_builtin(__builtin_amdgcn_fdot2)
  return __builtin_amdgcn_fdot2(__builtin_bit_cast(half2v, a),
                                __builtin_bit_cast(half2v, b), c, false);
#else
  half2v x = __builtin_bit_cast(half2v, a);
  half2v y = __builtin_bit_cast(half2v, b);
  return c + (float)x.x * (float)y.x + (float)x.y * (float)y.y;
#endif
}

// Pack ff1_w as wpk1[l][dp][o]  = half2(W1[o][2dp], W1[o][2dp+1])   (8192 u32)
// Pack ff2_w as wpk2[l][o][dhp] = half2(W2[o][2dhp], W2[o][2dhp+1]) (8192 u32)
__global__ void pack_weights_kernel(const float* __restrict__ ff1_w,
                                    const float* __restrict__ ff2_w,
                                    uint32_t* __restrict__ wpk1,
                                    uint32_t* __restrict__ wpk2) {
  int idx = blockIdx.x * blockDim.x + threadIdx.x;
  if (idx < 8192) {
    int l = idx >> 11, dp = (idx >> 6) & 31, o = idx & 63;
    wpk1[idx] = packh2(ff1_w[(l * 64 + o) * 64 + 2 * dp],
                       ff1_w[(l * 64 + o) * 64 + 2 * dp + 1]);
  } else if (idx < 16384) {
    int j = idx - 8192;
    int l = j >> 11, o = (j >> 5) & 63, dhp = j & 31;
    wpk2[j] = packh2(ff2_w[(l * 64 + o) * 64 + 2 * dhp],
                     ff2_w[(l * 64 + o) * 64 + 2 * dhp + 1]);
  }
}

// amdgpu_waves_per_eu(2,2): grid is 512 blocks = 2 blocks/CU = 2 waves/SIMD,
// so occupancy is grid-limited at 25% no matter what. Without the cap the
// allocator targeted 6 waves/EU (84 VGPRs) and spilled xpk[4][32] to scratch
// (~600 MB of HBM round-trip per dispatch: WRITE_SIZE 332 MB vs 4 MB output).
// Pinning to 2 waves/EU gives a 256-VGPR budget; peak live pressure (~200)
// fits, xpk stays register-resident.
__global__ __launch_bounds__(TPB)
__attribute__((amdgpu_waves_per_eu(2, 2))) void aat_kernel(
    const int* __restrict__ tokens, const float* __restrict__ emb,
    const float* __restrict__ lin_w, const float* __restrict__ lin_b,
    const float* __restrict__ ff1_b, const float* __restrict__ ff2_b,
    const float* __restrict__ n1_g, const float* __restrict__ n1_b,
    const float* __restrict__ n2_g, const float* __restrict__ n2_b,
    const float* __restrict__ out_w, const float* __restrict__ out_b,
    const uint32_t* __restrict__ wpk1, const uint32_t* __restrict__ wpk2,
    float* __restrict__ out) {
  // y/t2 buffer: [pair][thread] -> consecutive lanes hit consecutive banks.
  __shared__ uint32_t ybuf[32 * TPB];                 // 32 KiB
  __shared__ float red4[4][64];
  __shared__ float avgbuf[64];
  __shared__ __align__(8) float attnbuf[64];

  const int t = threadIdx.x;
  const int b = blockIdx.x;
  const int lane = t & 63;
  const int wv = t >> 6;

  uint32_t xpk[RPT][32];  // x rows, packed f16 pairs, register-resident

  // ---------------- embed * sqrt(d) + positional encoding ----------------
  #pragma unroll
  for (int r = 0; r < RPT; r++) {
    int s = t + r * TPB;
    if (s < 1000) {
      int tok = tokens[b * 1000 + s];
      const float4* ev = (const float4*)(emb + (size_t)tok * 64);
      #pragma unroll
      for (int q = 0; q < 16; q++) {
        float4 v4 = ev[q];
        float xv[4] = {v4.x, v4.y, v4.z, v4.w};
        #pragma unroll
        for (int j = 0; j < 4; j++) {
          int d = 4 * q + j;
          // div_i = 10000^(-i/32), i = d>>1 ; log2(10000)/32 = 0.41524101186
          float div = exp2f(-0.4152410118609203f * (float)(d >> 1));
          float ang = (float)s * div;
          float pe = (d & 1) ? cosf(ang) : sinf(ang);
          xv[j] = xv[j] * 8.0f + pe;
        }
        xpk[r][2 * q] = packh2(xv[0], xv[1]);
        xpk[r][2 * q + 1] = packh2(xv[2], xv[3]);
      }
    } else {
      #pragma unroll
      for (int dp = 0; dp < 32; dp++) xpk[r][dp] = 0u;  // masked rows stay 0
    }
  }

  for (int l = 0; l < NL; l++) {
    // ---------------- avg over sequence: butterfly reduce ----------------
    float v[64];
    #pragma unroll
    for (int dp = 0; dp < 32; dp++) {
      float s0 = 0.f, s1 = 0.f;
      #pragma unroll
      for (int r = 0; r < RPT; r++) {
        if (t + r * TPB < 1000) {  // masked rows contribute 0
          float2 xv = unpackh2(xpk[r][dp]);
          s0 += xv.x;
          s1 += xv.y;
        }
      }
      v[2 * dp] = s0;
      v[2 * dp + 1] = s1;
    }
    // 6-stage butterfly: lane ends holding channel==lane summed over wave
    #pragma unroll
    for (int m = 32; m >= 1; m >>= 1) {
      #pragma unroll
      for (int k = 0; k < m; k++) {
        bool up = (lane & m) != 0;
        float send = up ? v[k] : v[k + m];
        float keep = up ? v[k + m] : v[k];
        v[k] = keep + __shfl_xor(send, m, 64);
      }
    }
    __syncthreads();
    red4[wv][lane] = v[0];
    __syncthreads();
    if (t < 64)
      avgbuf[t] = (red4[0][t] + red4[1][t] + red4[2][t] + red4[3][t]) * 1e-3f;
    __syncthreads();
    if (t < 64) {  // attn[o] = lin_b[o] + sum_d avg[d]*lin_w[o][d]
      const float* wr = lin_w + (size_t)(l * 64 + t) * 64;
      float a0 = lin_b[l * 64 + t], a1 = 0.f, a2 = 0.f, a3 = 0.f;
      #pragma unroll
      for (int d = 0; d < 64; d += 4) {
        a0 += avgbuf[d] * wr[d];
        a1 += avgbuf[d + 1] * wr[d + 1];
        a2 += avgbuf[d + 2] * wr[d + 2];
        a3 += avgbuf[d + 3] * wr[d + 3];
      }
      attnbuf[t] = (a0 + a1) + (a2 + a3);
    }
    __syncthreads();

    // ---------------- per-row: LN1 -> FF -> LN2 ----------------
    #pragma unroll
    for (int r = 0; r < RPT; r++) {
      // LN1 stats over t = x + attn
      float m0 = 0.f, m1 = 0.f, q0 = 0.f, q1 = 0.f;
      #pragma unroll
      for (int dp = 0; dp < 32; dp++) {
        float2 xv = unpackh2(xpk[r][dp]);
        float2 at = ((const float2*)attnbuf)[dp];
        float a0 = xv.x + at.x, a1 = xv.y + at.y;
        m0 += a0;
        m1 += a1;
        q0 = fmaf(a0, a0, q0);
        q1 = fmaf(a1, a1, q1);
      }
      float mu = (m0 + m1) * (1.0f / 64.0f);
      float var = (q0 + q1) * (1.0f / 64.0f) - mu * mu;
      float rs = rsqrtf(var + 1e-5f);
      // LN1 normalize -> ybuf (f16 pairs)
      #pragma unroll
      for (int dp = 0; dp < 32; dp++) {
        float2 xv = unpackh2(xpk[r][dp]);
        float2 at = ((const float2*)attnbuf)[dp];
        float a0 = xv.x + at.x, a1 = xv.y + at.y;
        float y0 = fmaf((a0 - mu) * rs, n1_g[l * 64 + 2 * dp], n1_b[l * 64 + 2 * dp]);
        float y1 = fmaf((a1 - mu) * rs, n1_g[l * 64 + 2 * dp + 1], n1_b[l * 64 + 2 * dp + 1]);
        ybuf[dp * TPB + t] = packh2(y0, y1);
      }
      // mm1: h = relu(y @ W1^T + b1); 64 independent acc chains, scalar weights
      float acc[64];
      #pragma unroll
      for (int o = 0; o < 64; o++) acc[o] = ff1_b[l * 64 + o];
      for (int dp = 0; dp < 32; dp++) {
        uint32_t y2 = ybuf[dp * TPB + t];
        const uint32_t* wr = wpk1 + (l * 32 + dp) * 64;
        #pragma unroll
        for (int o = 0; o < 64; o++) acc[o] = fdot2h(y2, wr[o], acc[o]);
      }
      uint32_t hpk[32];
      #pragma unroll
      for (int dp = 0; dp < 32; dp++)
        hpk[dp] = packh2(fmaxf(acc[2 * dp], 0.f), fmaxf(acc[2 * dp + 1], 0.f));
      // mm2 + residual (in-place into ybuf) + LN2 stats
      float mm0 = 0.f, mm1v = 0.f, qq0 = 0.f, qq1 = 0.f;
      for (int op = 0; op < 32; op++) {
        const uint32_t* w0 = wpk2 + (size_t)(l * 64 + 2 * op) * 32;
        const uint32_t* w1 = w0 + 32;
        float a0 = ff2_b[l * 64 + 2 * op], a1 = ff2_b[l * 64 + 2 * op + 1];
        float b0 = 0.f, b1v = 0.f;
        #pragma unroll
        for (int dhp = 0; dhp < 32; dhp += 2) {
          a0 = fdot2h(hpk[dhp], w0[dhp], a0);
          b0 = fdot2h(hpk[dhp + 1], w0[dhp + 1], b0);
          a1 = fdot2h(hpk[dhp], w1[dhp], a1);
          b1v = fdot2h(hpk[dhp + 1], w1[dhp + 1], b1v);
        }
        a0 += b0;
        a1 += b1v;
        float2 yv = unpackh2(ybuf[op * TPB + t]);
        a0 += yv.x;
        a1 += yv.y;
        mm0 += a0;
        mm1v += a1;
        qq0 = fmaf(a0, a0, qq0);
        qq1 = fmaf(a1, a1, qq1);
        ybuf[op * TPB + t] = packh2(a0, a1);
      }
      mu = (mm0 + mm1v) * (1.0f / 64.0f);
      var = (qq0 + qq1) * (1.0f / 64.0f) - mu * mu;
      rs = rsqrtf(var + 1e-5f);
      // LN2 normalize -> xpk (next layer's x)
      #pragma unroll
      for (int dp = 0; dp < 32; dp++) {
        float2 tv = unpackh2(ybuf[dp * TPB + t]);
        float x0 = fmaf((tv.x - mu) * rs, n2_g[l * 64 + 2 * dp], n2_b[l * 64 + 2 * dp]);
        float x1 = fmaf((tv.y - mu) * rs, n2_g[l * 64 + 2 * dp + 1], n2_b[l * 64 + 2 * dp + 1]);
        xpk[r][dp] = packh2(x0, x1);
      }
    }
  }

  // ---------------- output projection [B,S,2] ----------------
  #pragma unroll
  for (int r = 0; r < RPT; r++) {
    int s = t + r * TPB;
    if (s < 1000) {
      float a0 = out_b[0], a1 = out_b[1];
      #pragma unroll
      for (int dp = 0; dp < 32; dp++) {
        float2 xv = unpackh2(xpk[r][dp]);
        a0 += xv.x * out_w[2 * dp] + xv.y * out_w[2 * dp + 1];
        a1 += xv.x * out_w[64 + 2 * dp] + xv.y * out_w[64 + 2 * dp + 1];
      }
      float2 res;
      res.x = a0;
      res.y = a1;
      *(float2*)(out + (size_t)(b * 1000 + s) * 2) = res;
    }
  }
}

extern "C" void kernel_launch(void* const* d_in, const int* in_sizes, int n_in,
                              void* d_out, int out_size, void* d_ws, size_t ws_size,
                              hipStream_t stream) {
  const int* tokens = (const int*)d_in[0];
  const float* emb = (const float*)d_in[1];
  const float* lin_w = (const float*)d_in[2];
  const float* lin_b = (const float*)d_in[3];
  const float* ff1_w = (const float*)d_in[4];
  const float* ff1_b = (const float*)d_in[5];
  const float* ff2_w = (const float*)d_in[6];
  const float* ff2_b = (const float*)d_in[7];
  const float* n1_g = (const float*)d_in[8];
  const float* n1_b = (const float*)d_in[9];
  const float* n2_g = (const float*)d_in[10];
  const float* n2_b = (const float*)d_in[11];
  const float* out_w = (const float*)d_in[12];
  const float* out_b = (const float*)d_in[13];
  float* out = (float*)d_out;

  uint32_t* wpk1 = (uint32_t*)d_ws;       // 32 KiB
  uint32_t* wpk2 = wpk1 + 4 * 32 * 64;    // 32 KiB

  pack_weights_kernel<<<64, TPB, 0, stream>>>(ff1_w, ff2_w, wpk1, wpk2);
  aat_kernel<<<512, TPB, 0, stream>>>(tokens, emb, lin_w, lin_b, ff1_b, ff2_b,
                                      n1_g, n1_b, n2_g, n2_b, out_w, out_b,
                                      wpk1, wpk2, out);
}

// Round 3
// 717.381 us; speedup vs baseline: 1.0220x; 1.0220x over previous
//
#include <hip/hip_runtime.h>
#include <stdint.h>

#define TPB 256
#define NL 4

typedef _Float16 half2v __attribute__((ext_vector_type(2)));

static __device__ __forceinline__ uint32_t packh2(float a, float b) {
  half2v h;
  h.x = (_Float16)a;
  h.y = (_Float16)b;
  return __builtin_bit_cast(uint32_t, h);
}
static __device__ __forceinline__ float2 unpackh2(uint32_t u) {
  half2v h = __builtin_bit_cast(half2v, u);
  return make_float2((float)h.x, (float)h.y);
}
static __device__ __forceinline__ float fdot2h(uint32_t a, uint32_t b, float c) {
#if __has_builtin(__builtin_amdgcn_fdot2)
  return __builtin_amdgcn_fdot2(__builtin_bit_cast(half2v, a),
                                __builtin_bit_cast(half2v, b), c, false);
#else
  half2v x = __builtin_bit_cast(half2v, a);
  half2v y = __builtin_bit_cast(half2v, b);
  return c + (float)x.x * (float)y.x + (float)x.y * (float)y.y;
#endif
}

// Pack ff1_w as wpk1[l][dp][o]  = half2(W1[o][2dp], W1[o][2dp+1])   (8192 u32)
// Pack ff2_w as wpk2[l][o][dhp] = half2(W2[o][2dhp], W2[o][2dhp+1]) (8192 u32)
// Also fill petab[s][d] = PE(s,d) for s<1000, d<64 (f32) when petab != nullptr.
__global__ void pack_weights_kernel(const float* __restrict__ ff1_w,
                                    const float* __restrict__ ff2_w,
                                    uint32_t* __restrict__ wpk1,
                                    uint32_t* __restrict__ wpk2,
                                    float* __restrict__ petab) {
  int idx = blockIdx.x * blockDim.x + threadIdx.x;
  if (idx < 8192) {
    int l = idx >> 11, dp = (idx >> 6) & 31, o = idx & 63;
    wpk1[idx] = packh2(ff1_w[(l * 64 + o) * 64 + 2 * dp],
                       ff1_w[(l * 64 + o) * 64 + 2 * dp + 1]);
  } else if (idx < 16384) {
    int j = idx - 8192;
    int l = j >> 11, o = (j >> 5) & 63, dhp = j & 31;
    wpk2[j] = packh2(ff2_w[(l * 64 + o) * 64 + 2 * dhp],
                     ff2_w[(l * 64 + o) * 64 + 2 * dhp + 1]);
  } else if (petab != nullptr && idx < 16384 + 64000) {
    int j = idx - 16384;
    int s = j >> 6, d = j & 63;
    // div_i = 10000^(-i/32), i = d>>1 ; log2(10000)/32 = 0.41524101186
    float div = exp2f(-0.4152410118609203f * (float)(d >> 1));
    float ang = (float)s * div;
    petab[j] = (d & 1) ? cosf(ang) : sinf(ang);
  }
}

// ---- per-row embed: xr = emb[tok]*8 + PE(s,:) packed as f16 pairs ----
static __device__ __forceinline__ void embed_row(uint32_t (&xr)[32], int b, int s,
                                                 bool valid,
                                                 const int* __restrict__ tokens,
                                                 const float* __restrict__ emb,
                                                 const float* __restrict__ petab) {
  if (!valid) {
    #pragma unroll
    for (int dp = 0; dp < 32; dp++) xr[dp] = 0u;
    return;
  }
  int tok = tokens[b * 1000 + s];
  const float4* ev = (const float4*)(emb + (size_t)tok * 64);
  if (petab != nullptr) {
    const float4* pv = (const float4*)(petab + (size_t)s * 64);
    #pragma unroll
    for (int q = 0; q < 16; q++) {
      float4 v4 = ev[q];
      float4 p4 = pv[q];
      xr[2 * q] = packh2(fmaf(v4.x, 8.f, p4.x), fmaf(v4.y, 8.f, p4.y));
      xr[2 * q + 1] = packh2(fmaf(v4.z, 8.f, p4.z), fmaf(v4.w, 8.f, p4.w));
    }
  } else {
    #pragma unroll
    for (int q = 0; q < 16; q++) {
      float4 v4 = ev[q];
      float xv[4] = {v4.x, v4.y, v4.z, v4.w};
      #pragma unroll
      for (int j = 0; j < 4; j++) {
        int d = 4 * q + j;
        float div = exp2f(-0.4152410118609203f * (float)(d >> 1));
        float ang = (float)s * div;
        float pe = (d & 1) ? cosf(ang) : sinf(ang);
        xv[j] = xv[j] * 8.0f + pe;
      }
      xr[2 * q] = packh2(xv[0], xv[1]);
      xr[2 * q + 1] = packh2(xv[2], xv[3]);
    }
  }
}

// ---- per-row layer body: LN1 -> FF(mm1 relu, mm2) + residual -> LN2 ----
// xr is a NAMED 32-u32 array reference; after inlining every access is a
// compile-time-constant index so SROA promotes it to VGPRs (the previous
// xpk[4][32] with a declined r-unroll was dynamically indexed -> scratch,
// 332 MB/dispatch of spill writes).
static __device__ __forceinline__ void process_row(
    uint32_t (&xr)[32], const int t, const int l,
    const float* __restrict__ ff1_b, const float* __restrict__ ff2_b,
    const float* __restrict__ n1_g, const float* __restrict__ n1_b,
    const float* __restrict__ n2_g, const float* __restrict__ n2_b,
    const uint32_t* __restrict__ wpk1, const uint32_t* __restrict__ wpk2,
    uint32_t* ybuf, const float* attnbuf) {
  // LN1 stats over v = x + attn
  float m0 = 0.f, m1 = 0.f, q0 = 0.f, q1 = 0.f;
  #pragma unroll
  for (int dp = 0; dp < 32; dp++) {
    float2 xv = unpackh2(xr[dp]);
    float2 at = ((const float2*)attnbuf)[dp];
    float a0 = xv.x + at.x, a1 = xv.y + at.y;
    m0 += a0;
    m1 += a1;
    q0 = fmaf(a0, a0, q0);
    q1 = fmaf(a1, a1, q1);
  }
  float mu = (m0 + m1) * (1.0f / 64.0f);
  float var = (q0 + q1) * (1.0f / 64.0f) - mu * mu;
  float rs = rsqrtf(var + 1e-5f);
  // LN1 normalize -> ybuf (f16 pairs)
  #pragma unroll
  for (int dp = 0; dp < 32; dp++) {
    float2 xv = unpackh2(xr[dp]);
    float2 at = ((const float2*)attnbuf)[dp];
    float a0 = xv.x + at.x, a1 = xv.y + at.y;
    float y0 = fmaf((a0 - mu) * rs, n1_g[l * 64 + 2 * dp], n1_b[l * 64 + 2 * dp]);
    float y1 = fmaf((a1 - mu) * rs, n1_g[l * 64 + 2 * dp + 1], n1_b[l * 64 + 2 * dp + 1]);
    ybuf[dp * TPB + t] = packh2(y0, y1);
  }
  // mm1: h = relu(y @ W1^T + b1), split into two 32-output halves to cap
  // register pressure (~210 peak incl. 4 x-rows) under the 256-VGPR budget.
  uint32_t hpk[32];
  #pragma unroll
  for (int h = 0; h < 2; h++) {
    float acc[32];
    #pragma unroll
    for (int o = 0; o < 32; o++) acc[o] = ff1_b[l * 64 + 32 * h + o];
    for (int dp = 0; dp < 32; dp++) {
      uint32_t y2 = ybuf[dp * TPB + t];
      const uint32_t* wr = wpk1 + (l * 32 + dp) * 64 + 32 * h;
      #pragma unroll
      for (int o = 0; o < 32; o++) acc[o] = fdot2h(y2, wr[o], acc[o]);
    }
    #pragma unroll
    for (int p = 0; p < 16; p++)
      hpk[16 * h + p] = packh2(fmaxf(acc[2 * p], 0.f), fmaxf(acc[2 * p + 1], 0.f));
  }
  // mm2 + residual (in-place into ybuf) + LN2 stats
  float mm0 = 0.f, mm1v = 0.f, qq0 = 0.f, qq1 = 0.f;
  for (int op = 0; op < 32; op++) {
    const uint32_t* w0 = wpk2 + (size_t)(l * 64 + 2 * op) * 32;
    const uint32_t* w1 = w0 + 32;
    float a0 = ff2_b[l * 64 + 2 * op], a1 = ff2_b[l * 64 + 2 * op + 1];
    float b0 = 0.f, b1v = 0.f;
    #pragma unroll
    for (int dhp = 0; dhp < 32; dhp += 2) {
      a0 = fdot2h(hpk[dhp], w0[dhp], a0);
      b0 = fdot2h(hpk[dhp + 1], w0[dhp + 1], b0);
      a1 = fdot2h(hpk[dhp], w1[dhp], a1);
      b1v = fdot2h(hpk[dhp + 1], w1[dhp + 1], b1v);
    }
    a0 += b0;
    a1 += b1v;
    float2 yv = unpackh2(ybuf[op * TPB + t]);
    a0 += yv.x;
    a1 += yv.y;
    mm0 += a0;
    mm1v += a1;
    qq0 = fmaf(a0, a0, qq0);
    qq1 = fmaf(a1, a1, qq1);
    ybuf[op * TPB + t] = packh2(a0, a1);
  }
  mu = (mm0 + mm1v) * (1.0f / 64.0f);
  var = (qq0 + qq1) * (1.0f / 64.0f) - mu * mu;
  rs = rsqrtf(var + 1e-5f);
  // LN2 normalize -> xr (next layer's x)
  #pragma unroll
  for (int dp = 0; dp < 32; dp++) {
    float2 tv = unpackh2(ybuf[dp * TPB + t]);
    float x0v = fmaf((tv.x - mu) * rs, n2_g[l * 64 + 2 * dp], n2_b[l * 64 + 2 * dp]);
    float x1v = fmaf((tv.y - mu) * rs, n2_g[l * 64 + 2 * dp + 1], n2_b[l * 64 + 2 * dp + 1]);
    xr[dp] = packh2(x0v, x1v);
  }
}

// ---- per-row output projection ----
static __device__ __forceinline__ void out_row(const uint32_t (&xr)[32],
                                               const float* ow0, const float* ow1,
                                               float ob0, float ob1,
                                               float* __restrict__ out,
                                               size_t idx) {
  float a0 = ob0, a1 = ob1;
  #pragma unroll
  for (int dp = 0; dp < 32; dp++) {
    float2 xv = unpackh2(xr[dp]);
    a0 += xv.x * ow0[2 * dp] + xv.y * ow0[2 * dp + 1];
    a1 += xv.x * ow1[2 * dp] + xv.y * ow1[2 * dp + 1];
  }
  float2 res = make_float2(a0, a1);
  *(float2*)(out + idx * 2) = res;
}

// Grid is 512 blocks = 2 blocks/CU = 2 waves/SIMD; __launch_bounds__(256,2)
// gives the allocator the full 256-VGPR budget at that occupancy.
__global__ __launch_bounds__(TPB, 2) void aat_kernel(
    const int* __restrict__ tokens, const float* __restrict__ emb,
    const float* __restrict__ lin_w, const float* __restrict__ lin_b,
    const float* __restrict__ ff1_b, const float* __restrict__ ff2_b,
    const float* __restrict__ n1_g, const float* __restrict__ n1_b,
    const float* __restrict__ n2_g, const float* __restrict__ n2_b,
    const float* __restrict__ out_w, const float* __restrict__ out_b,
    const uint32_t* __restrict__ wpk1, const uint32_t* __restrict__ wpk2,
    const float* __restrict__ petab, float* __restrict__ out) {
  // y/t2 buffer: [pair][thread] -> consecutive lanes hit consecutive banks.
  __shared__ uint32_t ybuf[32 * TPB];                 // 32 KiB
  __shared__ float red4[4][64];
  __shared__ float avgbuf[64];
  __shared__ __align__(8) float attnbuf[64];

  const int t = threadIdx.x;
  const int b = blockIdx.x;
  const int lane = t & 63;
  const int wv = t >> 6;

  // Four NAMED per-row x arrays (f16 pairs). Rows 0..2 (s = t, t+256, t+512)
  // are always valid (t <= 255 -> s <= 767); row 3 valid iff t < 232.
  uint32_t x0[32], x1[32], x2[32], x3[32];
  const bool r3v = (t < 232);

  // ---------------- embed * sqrt(d) + positional encoding ----------------
  embed_row(x0, b, t, true, tokens, emb, petab);
  embed_row(x1, b, t + TPB, true, tokens, emb, petab);
  embed_row(x2, b, t + 2 * TPB, true, tokens, emb, petab);
  embed_row(x3, b, t + 3 * TPB, r3v, tokens, emb, petab);

  for (int l = 0; l < NL; l++) {
    // ---------------- avg over sequence: butterfly reduce ----------------
    float v[64];
    #pragma unroll
    for (int dp = 0; dp < 32; dp++) {
      float2 a = unpackh2(x0[dp]);
      float2 bb = unpackh2(x1[dp]);
      float2 c = unpackh2(x2[dp]);
      float s0 = a.x + bb.x + c.x;
      float s1 = a.y + bb.y + c.y;
      if (r3v) {  // masked rows contribute 0
        float2 dd = unpackh2(x3[dp]);
        s0 += dd.x;
        s1 += dd.y;
      }
      v[2 * dp] = s0;
      v[2 * dp + 1] = s1;
    }
    // 6-stage butterfly: lane ends holding channel==lane summed over wave
    #pragma unroll
    for (int m = 32; m >= 1; m >>= 1) {
      #pragma unroll
      for (int k = 0; k < m; k++) {
        bool up = (lane & m) != 0;
        float send = up ? v[k] : v[k + m];
        float keep = up ? v[k + m] : v[k];
        v[k] = keep + __shfl_xor(send, m, 64);
      }
    }
    __syncthreads();
    red4[wv][lane] = v[0];
    __syncthreads();
    if (t < 64)
      avgbuf[t] = (red4[0][t] + red4[1][t] + red4[2][t] + red4[3][t]) * 1e-3f;
    __syncthreads();
    if (t < 64) {  // attn[o] = lin_b[o] + sum_d avg[d]*lin_w[o][d]
      const float* wr = lin_w + (size_t)(l * 64 + t) * 64;
      float a0 = lin_b[l * 64 + t], a1 = 0.f, a2 = 0.f, a3 = 0.f;
      #pragma unroll
      for (int d = 0; d < 64; d += 4) {
        a0 += avgbuf[d] * wr[d];
        a1 += avgbuf[d + 1] * wr[d + 1];
        a2 += avgbuf[d + 2] * wr[d + 2];
        a3 += avgbuf[d + 3] * wr[d + 3];
      }
      attnbuf[t] = (a0 + a1) + (a2 + a3);
    }
    __syncthreads();

    // ---------------- per-row: LN1 -> FF -> LN2 (hand-unrolled) ----------------
    process_row(x0, t, l, ff1_b, ff2_b, n1_g, n1_b, n2_g, n2_b, wpk1, wpk2, ybuf, attnbuf);
    process_row(x1, t, l, ff1_b, ff2_b, n1_g, n1_b, n2_g, n2_b, wpk1, wpk2, ybuf, attnbuf);
    process_row(x2, t, l, ff1_b, ff2_b, n1_g, n1_b, n2_g, n2_b, wpk1, wpk2, ybuf, attnbuf);
    process_row(x3, t, l, ff1_b, ff2_b, n1_g, n1_b, n2_g, n2_b, wpk1, wpk2, ybuf, attnbuf);
  }

  // ---------------- output projection [B,S,2] ----------------
  {
    float ow0[64], ow1[64];
    #pragma unroll
    for (int d = 0; d < 64; d++) {
      ow0[d] = out_w[d];
      ow1[d] = out_w[64 + d];
    }
    const float ob0 = out_b[0], ob1 = out_b[1];
    out_row(x0, ow0, ow1, ob0, ob1, out, (size_t)(b * 1000 + t));
    out_row(x1, ow0, ow1, ob0, ob1, out, (size_t)(b * 1000 + t + TPB));
    out_row(x2, ow0, ow1, ob0, ob1, out, (size_t)(b * 1000 + t + 2 * TPB));
    if (r3v)
      out_row(x3, ow0, ow1, ob0, ob1, out, (size_t)(b * 1000 + t + 3 * TPB));
  }
}

extern "C" void kernel_launch(void* const* d_in, const int* in_sizes, int n_in,
                              void* d_out, int out_size, void* d_ws, size_t ws_size,
                              hipStream_t stream) {
  const int* tokens = (const int*)d_in[0];
  const float* emb = (const float*)d_in[1];
  const float* lin_w = (const float*)d_in[2];
  const float* lin_b = (const float*)d_in[3];
  const float* ff1_w = (const float*)d_in[4];
  const float* ff1_b = (const float*)d_in[5];
  const float* ff2_w = (const float*)d_in[6];
  const float* ff2_b = (const float*)d_in[7];
  const float* n1_g = (const float*)d_in[8];
  const float* n1_b = (const float*)d_in[9];
  const float* n2_g = (const float*)d_in[10];
  const float* n2_b = (const float*)d_in[11];
  const float* out_w = (const float*)d_in[12];
  const float* out_b = (const float*)d_in[13];
  float* out = (float*)d_out;

  uint32_t* wpk1 = (uint32_t*)d_ws;       // 32 KiB
  uint32_t* wpk2 = wpk1 + 4 * 32 * 64;    // 32 KiB
  float* petab = (float*)(wpk2 + 4 * 64 * 32);  // 250 KiB (1000*64 f32)
  const size_t need = 16384 * 4 + 64000 * 4;
  const bool use_pe = (ws_size >= need);
  float* pe_arg = use_pe ? petab : nullptr;

  int pack_threads = 16384 + (use_pe ? 64000 : 0);
  int pack_blocks = (pack_threads + TPB - 1) / TPB;
  pack_weights_kernel<<<pack_blocks, TPB, 0, stream>>>(ff1_w, ff2_w, wpk1, wpk2, pe_arg);
  aat_kernel<<<512, TPB, 0, stream>>>(tokens, emb, lin_w, lin_b, ff1_b, ff2_b,
                                      n1_g, n1_b, n2_g, n2_b, out_w, out_b,
                                      wpk1, wpk2, pe_arg, out);
}

// Round 4
// 704.943 us; speedup vs baseline: 1.0400x; 1.0176x over previous
//
#include <hip/hip_runtime.h>
#include <stdint.h>

#define TPB 256
#define NL 4

// Textual unroll: every access to the persistent x arrays gets a LITERAL
// index so SROA/mem2reg promotion cannot be declined (pragma-unroll-based
// constant indices failed twice: WRITE_SIZE stayed at ~340 MB of scratch).
#define RPT16(M) M(0) M(1) M(2) M(3) M(4) M(5) M(6) M(7) \
                 M(8) M(9) M(10) M(11) M(12) M(13) M(14) M(15)
#define RPT32(M) RPT16(M) M(16) M(17) M(18) M(19) M(20) M(21) M(22) M(23) \
                 M(24) M(25) M(26) M(27) M(28) M(29) M(30) M(31)

typedef _Float16 half2v __attribute__((ext_vector_type(2)));

static __device__ __forceinline__ uint32_t packh2(float a, float b) {
  half2v h;
  h.x = (_Float16)a;
  h.y = (_Float16)b;
  return __builtin_bit_cast(uint32_t, h);
}
static __device__ __forceinline__ float2 unpackh2(uint32_t u) {
  half2v h = __builtin_bit_cast(half2v, u);
  return make_float2((float)h.x, (float)h.y);
}
static __device__ __forceinline__ float fdot2h(uint32_t a, uint32_t b, float c) {
#if __has_builtin(__builtin_amdgcn_fdot2)
  return __builtin_amdgcn_fdot2(__builtin_bit_cast(half2v, a),
                                __builtin_bit_cast(half2v, b), c, false);
#else
  half2v x = __builtin_bit_cast(half2v, a);
  half2v y = __builtin_bit_cast(half2v, b);
  return c + (float)x.x * (float)y.x + (float)x.y * (float)y.y;
#endif
}

// Pack ff1_w as wpk1[l][dp][o]  = half2(W1[o][2dp], W1[o][2dp+1])   (8192 u32)
// Pack ff2_w as wpk2[l][o][dhp] = half2(W2[o][2dhp], W2[o][2dhp+1]) (8192 u32)
// Also fill petab[s][d] = PE(s,d) for s<1000, d<64 (f32) when petab != nullptr.
__global__ void pack_weights_kernel(const float* __restrict__ ff1_w,
                                    const float* __restrict__ ff2_w,
                                    uint32_t* __restrict__ wpk1,
                                    uint32_t* __restrict__ wpk2,
                                    float* __restrict__ petab) {
  int idx = blockIdx.x * blockDim.x + threadIdx.x;
  if (idx < 8192) {
    int l = idx >> 11, dp = (idx >> 6) & 31, o = idx & 63;
    wpk1[idx] = packh2(ff1_w[(l * 64 + o) * 64 + 2 * dp],
                       ff1_w[(l * 64 + o) * 64 + 2 * dp + 1]);
  } else if (idx < 16384) {
    int j = idx - 8192;
    int l = j >> 11, o = (j >> 5) & 63, dhp = j & 31;
    wpk2[j] = packh2(ff2_w[(l * 64 + o) * 64 + 2 * dhp],
                     ff2_w[(l * 64 + o) * 64 + 2 * dhp + 1]);
  } else if (petab != nullptr && idx < 16384 + 64000) {
    int j = idx - 16384;
    int s = j >> 6, d = j & 63;
    // div_i = 10000^(-i/32), i = d>>1 ; log2(10000)/32 = 0.41524101186
    float div = exp2f(-0.4152410118609203f * (float)(d >> 1));
    float ang = (float)s * div;
    petab[j] = (d & 1) ? cosf(ang) : sinf(ang);
  }
}

// ---- per-row embed: xr = emb[tok]*8 + PE(s,:) packed as f16 pairs ----
static __device__ __forceinline__ void embed_row(uint32_t (&xr)[32], int b, int s,
                                                 bool valid,
                                                 const int* __restrict__ tokens,
                                                 const float* __restrict__ emb,
                                                 const float* __restrict__ petab) {
  if (!valid) {
#define ZERO_X(K) xr[K] = 0u;
    RPT32(ZERO_X)
#undef ZERO_X
    return;
  }
  int tok = tokens[b * 1000 + s];
  const float4* ev = (const float4*)(emb + (size_t)tok * 64);
  if (petab != nullptr) {
    const float4* pv = (const float4*)(petab + (size_t)s * 64);
#define EMB_Q(Q) { float4 v4 = ev[Q]; float4 p4 = pv[Q];                        \
    xr[2*(Q)]   = packh2(fmaf(v4.x, 8.f, p4.x), fmaf(v4.y, 8.f, p4.y));         \
    xr[2*(Q)+1] = packh2(fmaf(v4.z, 8.f, p4.z), fmaf(v4.w, 8.f, p4.w)); }
    RPT16(EMB_Q)
#undef EMB_Q
  } else {
    float fs = (float)s;
#define EMB_T(Q) { float4 v4 = ev[Q];                                           \
    float d0 = exp2f(-0.4152410118609203f * (float)((4*(Q)) >> 1));             \
    float d1 = exp2f(-0.4152410118609203f * (float)((4*(Q)+2) >> 1));           \
    float pe0 = sinf(fs*d0), pe1 = cosf(fs*d0);                                 \
    float pe2 = sinf(fs*d1), pe3 = cosf(fs*d1);                                 \
    xr[2*(Q)]   = packh2(fmaf(v4.x, 8.f, pe0), fmaf(v4.y, 8.f, pe1));           \
    xr[2*(Q)+1] = packh2(fmaf(v4.z, 8.f, pe2), fmaf(v4.w, 8.f, pe3)); }
    RPT16(EMB_T)
#undef EMB_T
  }
}

// ---- per-row layer body: LN1 -> FF(mm1 relu, mm2) + residual -> LN2 ----
// All xr accesses are literal-index (RPT32 textual expansion).
static __device__ __forceinline__ void process_row(
    uint32_t (&xr)[32], const int t, const int l,
    const float* __restrict__ ff1_b, const float* __restrict__ ff2_b,
    const float* __restrict__ n1_g, const float* __restrict__ n1_b,
    const float* __restrict__ n2_g, const float* __restrict__ n2_b,
    const uint32_t* __restrict__ wpk1, const uint32_t* __restrict__ wpk2,
    uint32_t* ybuf, const float* attnbuf) {
  const float2* at2 = (const float2*)attnbuf;
  const float* n1g = n1_g + l * 64;
  const float* n1b = n1_b + l * 64;
  const float* n2g = n2_g + l * 64;
  const float* n2b = n2_b + l * 64;

  // LN1 stats over v = x + attn
  float m0 = 0.f, m1 = 0.f, q0 = 0.f, q1 = 0.f;
#define LN1S(DP) { float2 xv = unpackh2(xr[DP]); float2 at = at2[DP];           \
    float a0 = xv.x + at.x, a1 = xv.y + at.y;                                   \
    m0 += a0; m1 += a1; q0 = fmaf(a0, a0, q0); q1 = fmaf(a1, a1, q1); }
  RPT32(LN1S)
#undef LN1S
  float mu = (m0 + m1) * (1.0f / 64.0f);
  float var = (q0 + q1) * (1.0f / 64.0f) - mu * mu;
  float rs = rsqrtf(var + 1e-5f);

  // LN1 normalize -> ybuf (f16 pairs); xr dead after this
#define LN1N(DP) { float2 xv = unpackh2(xr[DP]); float2 at = at2[DP];           \
    float a0 = xv.x + at.x, a1 = xv.y + at.y;                                   \
    float y0 = fmaf((a0 - mu) * rs, n1g[2*(DP)],   n1b[2*(DP)]);                \
    float y1 = fmaf((a1 - mu) * rs, n1g[2*(DP)+1], n1b[2*(DP)+1]);              \
    ybuf[(DP) * TPB + t] = packh2(y0, y1); }
  RPT32(LN1N)
#undef LN1N

  // mm1: h = relu(y @ W1^T + b1), two 32-output halves to cap pressure.
  uint32_t hpk[32];
  #pragma unroll
  for (int h = 0; h < 2; h++) {
    float acc[32];
    #pragma unroll
    for (int o = 0; o < 32; o++) acc[o] = ff1_b[l * 64 + 32 * h + o];
    for (int dp = 0; dp < 32; dp++) {
      uint32_t y2 = ybuf[dp * TPB + t];
      const uint32_t* wr = wpk1 + (l * 32 + dp) * 64 + 32 * h;
      #pragma unroll
      for (int o = 0; o < 32; o++) acc[o] = fdot2h(y2, wr[o], acc[o]);
    }
    #pragma unroll
    for (int p = 0; p < 16; p++)
      hpk[16 * h + p] = packh2(fmaxf(acc[2 * p], 0.f), fmaxf(acc[2 * p + 1], 0.f));
  }

  // mm2 + residual (in-place into ybuf) + LN2 stats
  float mm0 = 0.f, mm1v = 0.f, qq0 = 0.f, qq1 = 0.f;
  for (int op = 0; op < 32; op++) {
    const uint32_t* w0 = wpk2 + (size_t)(l * 64 + 2 * op) * 32;
    const uint32_t* w1 = w0 + 32;
    float a0 = ff2_b[l * 64 + 2 * op], a1 = ff2_b[l * 64 + 2 * op + 1];
    float b0 = 0.f, b1v = 0.f;
    #pragma unroll
    for (int dhp = 0; dhp < 32; dhp += 2) {
      a0 = fdot2h(hpk[dhp], w0[dhp], a0);
      b0 = fdot2h(hpk[dhp + 1], w0[dhp + 1], b0);
      a1 = fdot2h(hpk[dhp], w1[dhp], a1);
      b1v = fdot2h(hpk[dhp + 1], w1[dhp + 1], b1v);
    }
    a0 += b0;
    a1 += b1v;
    float2 yv = unpackh2(ybuf[op * TPB + t]);
    a0 += yv.x;
    a1 += yv.y;
    mm0 += a0;
    mm1v += a1;
    qq0 = fmaf(a0, a0, qq0);
    qq1 = fmaf(a1, a1, qq1);
    ybuf[op * TPB + t] = packh2(a0, a1);
  }
  float mu2 = (mm0 + mm1v) * (1.0f / 64.0f);
  float var2 = (qq0 + qq1) * (1.0f / 64.0f) - mu2 * mu2;
  float rs2 = rsqrtf(var2 + 1e-5f);

  // LN2 normalize -> xr (next layer's x)
#define LN2N(DP) { float2 tv = unpackh2(ybuf[(DP) * TPB + t]);                  \
    float x0v = fmaf((tv.x - mu2) * rs2, n2g[2*(DP)],   n2b[2*(DP)]);           \
    float x1v = fmaf((tv.y - mu2) * rs2, n2g[2*(DP)+1], n2b[2*(DP)+1]);         \
    xr[DP] = packh2(x0v, x1v); }
  RPT32(LN2N)
#undef LN2N
}

// ---- per-row output projection ----
static __device__ __forceinline__ void out_row(const uint32_t (&xr)[32],
                                               const float* __restrict__ out_w,
                                               float ob0, float ob1,
                                               float* __restrict__ out,
                                               size_t idx) {
  float a0 = ob0, a1 = ob1;
#define OUTD(DP) { float2 xv = unpackh2(xr[DP]);                                \
    a0 += xv.x * out_w[2*(DP)]      + xv.y * out_w[2*(DP)+1];                   \
    a1 += xv.x * out_w[64 + 2*(DP)] + xv.y * out_w[64 + 2*(DP)+1]; }
  RPT32(OUTD)
#undef OUTD
  *(float2*)(out + idx * 2) = make_float2(a0, a1);
}

// Grid is 512 blocks = 2 blocks/CU = 2 waves/SIMD; __launch_bounds__(256,2)
// gives the allocator the full 256-VGPR budget at that occupancy.
__global__ __launch_bounds__(TPB, 2) void aat_kernel(
    const int* __restrict__ tokens, const float* __restrict__ emb,
    const float* __restrict__ lin_w, const float* __restrict__ lin_b,
    const float* __restrict__ ff1_b, const float* __restrict__ ff2_b,
    const float* __restrict__ n1_g, const float* __restrict__ n1_b,
    const float* __restrict__ n2_g, const float* __restrict__ n2_b,
    const float* __restrict__ out_w, const float* __restrict__ out_b,
    const uint32_t* __restrict__ wpk1, const uint32_t* __restrict__ wpk2,
    const float* __restrict__ petab, float* __restrict__ out) {
  // y/t2 buffer: [pair][thread] -> consecutive lanes hit consecutive banks.
  __shared__ uint32_t ybuf[32 * TPB];                 // 32 KiB
  __shared__ float red4[4][64];
  __shared__ float avgbuf[64];
  __shared__ __align__(8) float attnbuf[64];

  const int t = threadIdx.x;
  const int b = blockIdx.x;
  const int lane = t & 63;
  const int wv = t >> 6;

  // Four per-row x arrays (f16 pairs), all accesses literal-index.
  // Rows 0..2 (s = t, t+256, t+512) always valid; row 3 valid iff t < 232.
  uint32_t x0[32], x1[32], x2[32], x3[32];
  const bool r3v = (t < 232);

  // ---------------- embed * sqrt(d) + positional encoding ----------------
  embed_row(x0, b, t, true, tokens, emb, petab);
  embed_row(x1, b, t + TPB, true, tokens, emb, petab);
  embed_row(x2, b, t + 2 * TPB, true, tokens, emb, petab);
  embed_row(x3, b, t + 3 * TPB, r3v, tokens, emb, petab);

  for (int l = 0; l < NL; l++) {
    // ---------------- avg over sequence: butterfly reduce ----------------
    float v[64];
#define AVGD(DP) { float2 a = unpackh2(x0[DP]); float2 bb = unpackh2(x1[DP]);   \
    float2 c = unpackh2(x2[DP]);                                                \
    float s0 = a.x + bb.x + c.x, s1 = a.y + bb.y + c.y;                         \
    if (r3v) { float2 dd = unpackh2(x3[DP]); s0 += dd.x; s1 += dd.y; }          \
    v[2*(DP)] = s0; v[2*(DP)+1] = s1; }
    RPT32(AVGD)
#undef AVGD
    // 6-stage butterfly: lane ends holding channel==lane summed over wave
    #pragma unroll
    for (int m = 32; m >= 1; m >>= 1) {
      #pragma unroll
      for (int k = 0; k < m; k++) {
        bool up = (lane & m) != 0;
        float send = up ? v[k] : v[k + m];
        float keep = up ? v[k + m] : v[k];
        v[k] = keep + __shfl_xor(send, m, 64);
      }
    }
    __syncthreads();
    red4[wv][lane] = v[0];
    __syncthreads();
    if (t < 64)
      avgbuf[t] = (red4[0][t] + red4[1][t] + red4[2][t] + red4[3][t]) * 1e-3f;
    __syncthreads();
    if (t < 64) {  // attn[o] = lin_b[o] + sum_d avg[d]*lin_w[o][d]
      const float* wr = lin_w + (size_t)(l * 64 + t) * 64;
      float a0 = lin_b[l * 64 + t], a1 = 0.f, a2 = 0.f, a3 = 0.f;
      #pragma unroll
      for (int d = 0; d < 64; d += 4) {
        a0 += avgbuf[d] * wr[d];
        a1 += avgbuf[d + 1] * wr[d + 1];
        a2 += avgbuf[d + 2] * wr[d + 2];
        a3 += avgbuf[d + 3] * wr[d + 3];
      }
      attnbuf[t] = (a0 + a1) + (a2 + a3);
    }
    __syncthreads();

    // ---------------- per-row: LN1 -> FF -> LN2 (hand-unrolled) ----------------
    process_row(x0, t, l, ff1_b, ff2_b, n1_g, n1_b, n2_g, n2_b, wpk1, wpk2, ybuf, attnbuf);
    process_row(x1, t, l, ff1_b, ff2_b, n1_g, n1_b, n2_g, n2_b, wpk1, wpk2, ybuf, attnbuf);
    process_row(x2, t, l, ff1_b, ff2_b, n1_g, n1_b, n2_g, n2_b, wpk1, wpk2, ybuf, attnbuf);
    process_row(x3, t, l, ff1_b, ff2_b, n1_g, n1_b, n2_g, n2_b, wpk1, wpk2, ybuf, attnbuf);
  }

  // ---------------- output projection [B,S,2] ----------------
  {
    const float ob0 = out_b[0], ob1 = out_b[1];
    out_row(x0, out_w, ob0, ob1, out, (size_t)(b * 1000 + t));
    out_row(x1, out_w, ob0, ob1, out, (size_t)(b * 1000 + t + TPB));
    out_row(x2, out_w, ob0, ob1, out, (size_t)(b * 1000 + t + 2 * TPB));
    if (r3v)
      out_row(x3, out_w, ob0, ob1, out, (size_t)(b * 1000 + t + 3 * TPB));
  }
}

extern "C" void kernel_launch(void* const* d_in, const int* in_sizes, int n_in,
                              void* d_out, int out_size, void* d_ws, size_t ws_size,
                              hipStream_t stream) {
  const int* tokens = (const int*)d_in[0];
  const float* emb = (const float*)d_in[1];
  const float* lin_w = (const float*)d_in[2];
  const float* lin_b = (const float*)d_in[3];
  const float* ff1_w = (const float*)d_in[4];
  const float* ff1_b = (const float*)d_in[5];
  const float* ff2_w = (const float*)d_in[6];
  const float* ff2_b = (const float*)d_in[7];
  const float* n1_g = (const float*)d_in[8];
  const float* n1_b = (const float*)d_in[9];
  const float* n2_g = (const float*)d_in[10];
  const float* n2_b = (const float*)d_in[11];
  const float* out_w = (const float*)d_in[12];
  const float* out_b = (const float*)d_in[13];
  float* out = (float*)d_out;

  uint32_t* wpk1 = (uint32_t*)d_ws;       // 32 KiB
  uint32_t* wpk2 = wpk1 + 4 * 32 * 64;    // 32 KiB
  float* petab = (float*)(wpk2 + 4 * 64 * 32);  // 250 KiB (1000*64 f32)
  const size_t need = 16384 * 4 + 64000 * 4;
  const bool use_pe = (ws_size >= need);
  float* pe_arg = use_pe ? petab : nullptr;

  int pack_threads = 16384 + (use_pe ? 64000 : 0);
  int pack_blocks = (pack_threads + TPB - 1) / TPB;
  pack_weights_kernel<<<pack_blocks, TPB, 0, stream>>>(ff1_w, ff2_w, wpk1, wpk2, pe_arg);
  aat_kernel<<<512, TPB, 0, stream>>>(tokens, emb, lin_w, lin_b, ff1_b, ff2_b,
                                      n1_g, n1_b, n2_g, n2_b, out_w, out_b,
                                      wpk1, wpk2, pe_arg, out);
}

// Round 5
// 643.597 us; speedup vs baseline: 1.1392x; 1.0953x over previous
//
#include <hip/hip_runtime.h>
#include <stdint.h>

#define TPB 1024
#define NL 4

// Textual unroll macros: every access to per-thread register arrays gets a
// LITERAL index (runtime-indexed local arrays are demoted to scratch).
#define RPT16(M) M(0) M(1) M(2) M(3) M(4) M(5) M(6) M(7) \
                 M(8) M(9) M(10) M(11) M(12) M(13) M(14) M(15)
#define RPT32(M) RPT16(M) M(16) M(17) M(18) M(19) M(20) M(21) M(22) M(23) \
                 M(24) M(25) M(26) M(27) M(28) M(29) M(30) M(31)
#define RPT8x(M) M(0) M(1) M(2) M(3) M(4) M(5) M(6) M(7)
#define RPT4x(M) M(0) M(1) M(2) M(3)
#define RPT2x(M) M(0) M(1)

typedef _Float16 half2v __attribute__((ext_vector_type(2)));

static __device__ __forceinline__ uint32_t packh2(float a, float b) {
  half2v h;
  h.x = (_Float16)a;
  h.y = (_Float16)b;
  return __builtin_bit_cast(uint32_t, h);
}
static __device__ __forceinline__ float2 unpackh2(uint32_t u) {
  half2v h = __builtin_bit_cast(half2v, u);
  return make_float2((float)h.x, (float)h.y);
}
static __device__ __forceinline__ float fdot2h(uint32_t a, uint32_t b, float c) {
#if __has_builtin(__builtin_amdgcn_fdot2)
  return __builtin_amdgcn_fdot2(__builtin_bit_cast(half2v, a),
                                __builtin_bit_cast(half2v, b), c, false);
#else
  half2v x = __builtin_bit_cast(half2v, a);
  half2v y = __builtin_bit_cast(half2v, b);
  return c + (float)x.x * (float)y.x + (float)x.y * (float)y.y;
#endif
}

// Pack ff1_w as wpk1[l][dp][o]  = half2(W1[o][2dp], W1[o][2dp+1])   (8192 u32)
// Pack ff2_w as wpk2[l][o][dhp] = half2(W2[o][2dhp], W2[o][2dhp+1]) (8192 u32)
// Also fill petab[s][d] = PE(s,d) for s<1000, d<64 (f32) when petab != nullptr.
__global__ void pack_weights_kernel(const float* __restrict__ ff1_w,
                                    const float* __restrict__ ff2_w,
                                    uint32_t* __restrict__ wpk1,
                                    uint32_t* __restrict__ wpk2,
                                    float* __restrict__ petab) {
  int idx = blockIdx.x * blockDim.x + threadIdx.x;
  if (idx < 8192) {
    int l = idx >> 11, dp = (idx >> 6) & 31, o = idx & 63;
    wpk1[idx] = packh2(ff1_w[(l * 64 + o) * 64 + 2 * dp],
                       ff1_w[(l * 64 + o) * 64 + 2 * dp + 1]);
  } else if (idx < 16384) {
    int j = idx - 8192;
    int l = j >> 11, o = (j >> 5) & 63, dhp = j & 31;
    wpk2[j] = packh2(ff2_w[(l * 64 + o) * 64 + 2 * dhp],
                     ff2_w[(l * 64 + o) * 64 + 2 * dhp + 1]);
  } else if (petab != nullptr && idx < 16384 + 64000) {
    int j = idx - 16384;
    int s = j >> 6, d = j & 63;
    // div_i = 10000^(-i/32), i = d>>1 ; log2(10000)/32 = 0.41524101186
    float div = exp2f(-0.4152410118609203f * (float)(d >> 1));
    float ang = (float)s * div;
    petab[j] = (d & 1) ? cosf(ang) : sinf(ang);
  }
}

// One row per thread: per-thread persistent state is x[32] (64 ch, f16 pairs)
// -- the same size class as the arrays that have promoted reliably.
// 512 blocks x 1024 threads; block b owns batch b; thread t owns row t (t<1000).
// __launch_bounds__(1024): 16-wave block must be CU-resident -> VGPR <= 128.
__global__ __launch_bounds__(TPB) void aat_kernel(
    const int* __restrict__ tokens, const float* __restrict__ emb,
    const float* __restrict__ lin_w, const float* __restrict__ lin_b,
    const float* __restrict__ ff1_b, const float* __restrict__ ff2_b,
    const float* __restrict__ n1_g, const float* __restrict__ n1_b,
    const float* __restrict__ n2_g, const float* __restrict__ n2_b,
    const float* __restrict__ out_w, const float* __restrict__ out_b,
    const uint32_t* __restrict__ wpk1, const uint32_t* __restrict__ wpk2,
    const float* __restrict__ petab, float* __restrict__ out) {
  __shared__ float redw[16][64];                      // 4 KiB
  __shared__ float avgbuf[64];
  __shared__ __align__(8) float attnbuf[64];

  const int t = threadIdx.x;
  const int b = blockIdx.x;
  const int lane = t & 63;
  const int wv = t >> 6;        // 0..15
  const bool valid = (t < 1000);

  uint32_t x[32];               // this thread's row, f16 pairs
  uint32_t y[32];               // LN1 output / mm2 result (reused)

  // ---------------- embed * sqrt(d) + positional encoding ----------------
  if (valid) {
    int tok = tokens[b * 1000 + t];
    const float4* ev = (const float4*)(emb + (size_t)tok * 64);
    if (petab != nullptr) {
      const float4* pv = (const float4*)(petab + (size_t)t * 64);
#define EMBQ(Q) { float4 v4 = ev[Q]; float4 p4 = pv[Q];                         \
      x[2*(Q)]   = packh2(fmaf(v4.x, 8.f, p4.x), fmaf(v4.y, 8.f, p4.y));        \
      x[2*(Q)+1] = packh2(fmaf(v4.z, 8.f, p4.z), fmaf(v4.w, 8.f, p4.w)); }
      RPT16(EMBQ)
#undef EMBQ
    } else {
      float fs = (float)t;
#define EMBT(Q) { float4 v4 = ev[Q];                                            \
      float d0 = exp2f(-0.4152410118609203f * (float)((4*(Q)) >> 1));           \
      float d1 = exp2f(-0.4152410118609203f * (float)((4*(Q)+2) >> 1));         \
      float pe0 = sinf(fs*d0), pe1 = cosf(fs*d0);                               \
      float pe2 = sinf(fs*d1), pe3 = cosf(fs*d1);                               \
      x[2*(Q)]   = packh2(fmaf(v4.x, 8.f, pe0), fmaf(v4.y, 8.f, pe1));          \
      x[2*(Q)+1] = packh2(fmaf(v4.z, 8.f, pe2), fmaf(v4.w, 8.f, pe3)); }
      RPT16(EMBT)
#undef EMBT
    }
  } else {
#define ZX(K) x[K] = 0u;
    RPT32(ZX)
#undef ZX
  }

  for (int l = 0; l < NL; l++) {
    const float* n1g = n1_g + l * 64;
    const float* n1b = n1_b + l * 64;
    const float* n2g = n2_g + l * 64;
    const float* n2b = n2_b + l * 64;
    const float* f1b = ff1_b + l * 64;
    const float* f2b = ff2_b + l * 64;
    const uint32_t* w1base = wpk1 + l * 2048;   // [dp][64]
    const uint32_t* w2base = wpk2 + l * 2048;   // [o][32]

    // ------------- avg over sequence: wave butterfly + LDS cross-wave -------------
    {
      float v[64];
#define AVGD(DP) { float2 a = valid ? unpackh2(x[DP]) : make_float2(0.f, 0.f);  \
      v[2*(DP)] = a.x; v[2*(DP)+1] = a.y; }
      RPT32(AVGD)
#undef AVGD
      // 6-stage butterfly, fully literal: lane ends holding channel==lane
#define BF(MM, K) { bool up = (lane & (MM)) != 0;                               \
      float snd = up ? v[K] : v[(K)+(MM)];                                      \
      float kp  = up ? v[(K)+(MM)] : v[K];                                      \
      v[K] = kp + __shfl_xor(snd, (MM), 64); }
#define BF32(K) BF(32, K)
#define BF16(K) BF(16, K)
#define BF8(K) BF(8, K)
#define BF4(K) BF(4, K)
#define BF2(K) BF(2, K)
      RPT32(BF32)
      RPT16(BF16)
      RPT8x(BF8)
      RPT4x(BF4)
      RPT2x(BF2)
      BF(1, 0)
#undef BF2
#undef BF4
#undef BF8
#undef BF16
#undef BF32
#undef BF
      __syncthreads();
      redw[wv][lane] = v[0];
      __syncthreads();
    }
    if (t < 64) {
      float s = 0.f;
      #pragma unroll
      for (int w = 0; w < 16; w++) s += redw[w][t];
      avgbuf[t] = s * 1e-3f;
    }
    __syncthreads();
    if (t < 64) {  // attn[o] = lin_b[o] + sum_d avg[d]*lin_w[o][d]
      const float* wr = lin_w + (size_t)(l * 64 + t) * 64;
      float a0 = lin_b[l * 64 + t], a1 = 0.f, a2 = 0.f, a3 = 0.f;
      #pragma unroll
      for (int d = 0; d < 64; d += 4) {
        a0 += avgbuf[d] * wr[d];
        a1 += avgbuf[d + 1] * wr[d + 1];
        a2 += avgbuf[d + 2] * wr[d + 2];
        a3 += avgbuf[d + 3] * wr[d + 3];
      }
      attnbuf[t] = (a0 + a1) + (a2 + a3);
    }
    __syncthreads();

    const float2* at2 = (const float2*)attnbuf;

    // ---------------- LN1 stats over v = x + attn ----------------
    float m0 = 0.f, m1 = 0.f, q0 = 0.f, q1 = 0.f;
#define LN1S(DP) { float2 xv = unpackh2(x[DP]); float2 at = at2[DP];            \
    float a0 = xv.x + at.x, a1 = xv.y + at.y;                                   \
    m0 += a0; m1 += a1; q0 = fmaf(a0, a0, q0); q1 = fmaf(a1, a1, q1); }
    RPT32(LN1S)
#undef LN1S
    float mu = (m0 + m1) * (1.0f / 64.0f);
    float var = (q0 + q1) * (1.0f / 64.0f) - mu * mu;
    float rs = rsqrtf(var + 1e-5f);

    // ---------------- LN1 normalize -> y (registers); x dead after ----------------
#define LN1N(DP) { float2 xv = unpackh2(x[DP]); float2 at = at2[DP];            \
    float a0 = xv.x + at.x, a1 = xv.y + at.y;                                   \
    float y0 = fmaf((a0 - mu) * rs, n1g[2*(DP)],   n1b[2*(DP)]);                \
    float y1 = fmaf((a1 - mu) * rs, n1g[2*(DP)+1], n1b[2*(DP)+1]);              \
    y[DP] = packh2(y0, y1); }
    RPT32(LN1N)
#undef LN1N

    // ---------------- mm1: h = relu(y @ W1^T + b1), two 32-output halves ----------------
    uint32_t hpk[32];
    {
      float acc[32];
      #pragma unroll
      for (int o = 0; o < 32; o++) acc[o] = f1b[o];
#define MM1D(DP) { uint32_t yv = y[DP]; const uint32_t* wr = w1base + (DP)*64;  \
      _Pragma("unroll") for (int o = 0; o < 32; o++)                            \
        acc[o] = fdot2h(yv, wr[o], acc[o]); }
      RPT32(MM1D)
#undef MM1D
      #pragma unroll
      for (int p = 0; p < 16; p++)
        hpk[p] = packh2(fmaxf(acc[2*p], 0.f), fmaxf(acc[2*p+1], 0.f));
    }
    {
      float acc[32];
      #pragma unroll
      for (int o = 0; o < 32; o++) acc[o] = f1b[32 + o];
#define MM1D(DP) { uint32_t yv = y[DP]; const uint32_t* wr = w1base + (DP)*64 + 32; \
      _Pragma("unroll") for (int o = 0; o < 32; o++)                            \
        acc[o] = fdot2h(yv, wr[o], acc[o]); }
      RPT32(MM1D)
#undef MM1D
      #pragma unroll
      for (int p = 0; p < 16; p++)
        hpk[16 + p] = packh2(fmaxf(acc[2*p], 0.f), fmaxf(acc[2*p+1], 0.f));
    }

    // ---------------- mm2 + residual (y) + LN2 stats; result back into y ----------------
    float mm0 = 0.f, mm1v = 0.f, qq0 = 0.f, qq1 = 0.f;
#define MM2O(OP) { const uint32_t* w0 = w2base + (OP)*64;                       \
    const uint32_t* w1p = w0 + 32;                                              \
    float a0 = f2b[2*(OP)], a1 = f2b[2*(OP)+1];                                 \
    float b0 = 0.f, b1v = 0.f;                                                  \
    _Pragma("unroll") for (int dhp = 0; dhp < 32; dhp += 2) {                   \
      a0  = fdot2h(hpk[dhp],     w0[dhp],      a0);                             \
      b0  = fdot2h(hpk[dhp + 1], w0[dhp + 1],  b0);                             \
      a1  = fdot2h(hpk[dhp],     w1p[dhp],     a1);                             \
      b1v = fdot2h(hpk[dhp + 1], w1p[dhp + 1], b1v);                            \
    }                                                                           \
    a0 += b0; a1 += b1v;                                                        \
    float2 yv2 = unpackh2(y[OP]);                                               \
    a0 += yv2.x; a1 += yv2.y;                                                   \
    mm0 += a0; mm1v += a1;                                                      \
    qq0 = fmaf(a0, a0, qq0); qq1 = fmaf(a1, a1, qq1);                           \
    y[OP] = packh2(a0, a1); }
    RPT32(MM2O)
#undef MM2O
    float mu2 = (mm0 + mm1v) * (1.0f / 64.0f);
    float var2 = (qq0 + qq1) * (1.0f / 64.0f) - mu2 * mu2;
    float rs2 = rsqrtf(var2 + 1e-5f);

    // ---------------- LN2 normalize -> x (next layer) ----------------
#define LN2N(DP) { float2 tv = unpackh2(y[DP]);                                 \
    float x0v = fmaf((tv.x - mu2) * rs2, n2g[2*(DP)],   n2b[2*(DP)]);           \
    float x1v = fmaf((tv.y - mu2) * rs2, n2g[2*(DP)+1], n2b[2*(DP)+1]);         \
    x[DP] = packh2(x0v, x1v); }
    RPT32(LN2N)
#undef LN2N
  }

  // ---------------- output projection [B,S,2] ----------------
  if (valid) {
    float a0 = out_b[0], a1 = out_b[1];
#define OUTD(DP) { float2 xv = unpackh2(x[DP]);                                 \
    a0 += xv.x * out_w[2*(DP)]      + xv.y * out_w[2*(DP)+1];                   \
    a1 += xv.x * out_w[64 + 2*(DP)] + xv.y * out_w[64 + 2*(DP)+1]; }
    RPT32(OUTD)
#undef OUTD
    *(float2*)(out + (size_t)(b * 1000 + t) * 2) = make_float2(a0, a1);
  }
}

extern "C" void kernel_launch(void* const* d_in, const int* in_sizes, int n_in,
                              void* d_out, int out_size, void* d_ws, size_t ws_size,
                              hipStream_t stream) {
  const int* tokens = (const int*)d_in[0];
  const float* emb = (const float*)d_in[1];
  const float* lin_w = (const float*)d_in[2];
  const float* lin_b = (const float*)d_in[3];
  const float* ff1_w = (const float*)d_in[4];
  const float* ff1_b = (const float*)d_in[5];
  const float* ff2_w = (const float*)d_in[6];
  const float* ff2_b = (const float*)d_in[7];
  const float* n1_g = (const float*)d_in[8];
  const float* n1_b = (const float*)d_in[9];
  const float* n2_g = (const float*)d_in[10];
  const float* n2_b = (const float*)d_in[11];
  const float* out_w = (const float*)d_in[12];
  const float* out_b = (const float*)d_in[13];
  float* out = (float*)d_out;

  uint32_t* wpk1 = (uint32_t*)d_ws;       // 32 KiB
  uint32_t* wpk2 = wpk1 + 4 * 32 * 64;    // 32 KiB
  float* petab = (float*)(wpk2 + 4 * 64 * 32);  // 250 KiB (1000*64 f32)
  const size_t need = 16384 * 4 + 64000 * 4;
  const bool use_pe = (ws_size >= need);
  float* pe_arg = use_pe ? petab : nullptr;

  int pack_threads = 16384 + (use_pe ? 64000 : 0);
  int pack_blocks = (pack_threads + 255) / 256;
  pack_weights_kernel<<<pack_blocks, 256, 0, stream>>>(ff1_w, ff2_w, wpk1, wpk2, pe_arg);
  aat_kernel<<<512, TPB, 0, stream>>>(tokens, emb, lin_w, lin_b, ff1_b, ff2_b,
                                      n1_g, n1_b, n2_g, n2_b, out_w, out_b,
                                      wpk1, wpk2, pe_arg, out);
}

// Round 6
// 641.384 us; speedup vs baseline: 1.1431x; 1.0035x over previous
//
#include <hip/hip_runtime.h>
#include <stdint.h>

#define TPB 1024
#define NL 4

// Textual unroll macros: every access to per-thread register arrays gets a
// LITERAL index (runtime-indexed local arrays are demoted to scratch).
#define RPT16(M) M(0) M(1) M(2) M(3) M(4) M(5) M(6) M(7) \
                 M(8) M(9) M(10) M(11) M(12) M(13) M(14) M(15)
#define RPT32(M) RPT16(M) M(16) M(17) M(18) M(19) M(20) M(21) M(22) M(23) \
                 M(24) M(25) M(26) M(27) M(28) M(29) M(30) M(31)
#define RPT8x(M) M(0) M(1) M(2) M(3) M(4) M(5) M(6) M(7)
#define RPT4x(M) M(0) M(1) M(2) M(3)
#define RPT2x(M) M(0) M(1)

typedef _Float16 half2v __attribute__((ext_vector_type(2)));

static __device__ __forceinline__ uint32_t packh2(float a, float b) {
  half2v h;
  h.x = (_Float16)a;
  h.y = (_Float16)b;
  return __builtin_bit_cast(uint32_t, h);
}
static __device__ __forceinline__ float2 unpackh2(uint32_t u) {
  half2v h = __builtin_bit_cast(half2v, u);
  return make_float2((float)h.x, (float)h.y);
}
static __device__ __forceinline__ float fdot2h(uint32_t a, uint32_t b, float c) {
#if __has_builtin(__builtin_amdgcn_fdot2)
  return __builtin_amdgcn_fdot2(__builtin_bit_cast(half2v, a),
                                __builtin_bit_cast(half2v, b), c, false);
#else
  half2v x = __builtin_bit_cast(half2v, a);
  half2v y = __builtin_bit_cast(half2v, b);
  return c + (float)x.x * (float)y.x + (float)x.y * (float)y.y;
#endif
}

// Pack ff1_w as wpk1[l][dp][o]  = half2(W1[o][2dp], W1[o][2dp+1])   (8192 u32)
// Pack ff2_w as wpk2[l][o][dhp] = half2(W2[o][2dhp], W2[o][2dhp+1]) (8192 u32)
// Also fill petab[s][d] = PE(s,d) for s<1000, d<64 (f32) when petab != nullptr.
__global__ void pack_weights_kernel(const float* __restrict__ ff1_w,
                                    const float* __restrict__ ff2_w,
                                    uint32_t* __restrict__ wpk1,
                                    uint32_t* __restrict__ wpk2,
                                    float* __restrict__ petab) {
  int idx = blockIdx.x * blockDim.x + threadIdx.x;
  if (idx < 8192) {
    int l = idx >> 11, dp = (idx >> 6) & 31, o = idx & 63;
    wpk1[idx] = packh2(ff1_w[(l * 64 + o) * 64 + 2 * dp],
                       ff1_w[(l * 64 + o) * 64 + 2 * dp + 1]);
  } else if (idx < 16384) {
    int j = idx - 8192;
    int l = j >> 11, o = (j >> 5) & 63, dhp = j & 31;
    wpk2[j] = packh2(ff2_w[(l * 64 + o) * 64 + 2 * dhp],
                     ff2_w[(l * 64 + o) * 64 + 2 * dhp + 1]);
  } else if (petab != nullptr && idx < 16384 + 64000) {
    int j = idx - 16384;
    int s = j >> 6, d = j & 63;
    // div_i = 10000^(-i/32), i = d>>1 ; log2(10000)/32 = 0.41524101186
    float div = exp2f(-0.4152410118609203f * (float)(d >> 1));
    float ang = (float)s * div;
    petab[j] = (d & 1) ? cosf(ang) : sinf(ang);
  }
}

// One row per thread; per-thread persistent state is x[32] (64 ch, f16 pairs).
// amdgpu_waves_per_eu(4,4): a 1024-thread block is 16 waves = exactly 4/EU,
// pinning the VGPR budget at 512/4 = 128. (R5's heuristic chose 8 waves/EU ->
// 64 VGPRs -> all arrays in scratch, 252 MB/dispatch of spill writes. Note
// (2,2) would be illegal here: 256-reg waves can't co-reside 16 to a CU.)
// Peak live pressure by phase: avg ~70 (x32+v32), mm1 ~116 (y32+acc32+hpk32),
// mm2 ~80 -- all under 128.
__global__ __launch_bounds__(TPB)
__attribute__((amdgpu_waves_per_eu(4, 4))) void aat_kernel(
    const int* __restrict__ tokens, const float* __restrict__ emb,
    const float* __restrict__ lin_w, const float* __restrict__ lin_b,
    const float* __restrict__ ff1_b, const float* __restrict__ ff2_b,
    const float* __restrict__ n1_g, const float* __restrict__ n1_b,
    const float* __restrict__ n2_g, const float* __restrict__ n2_b,
    const float* __restrict__ out_w, const float* __restrict__ out_b,
    const uint32_t* __restrict__ wpk1, const uint32_t* __restrict__ wpk2,
    const float* __restrict__ petab, float* __restrict__ out) {
  __shared__ float redw[16][64];                      // 4 KiB
  __shared__ float avgbuf[64];
  __shared__ __align__(8) float attnbuf[64];

  const int t = threadIdx.x;
  const int b = blockIdx.x;
  const int lane = t & 63;
  const int wv = t >> 6;        // 0..15
  const bool valid = (t < 1000);

  uint32_t x[32];               // this thread's row, f16 pairs
  uint32_t y[32];               // LN1 output / mm2 result (reused)

  // ---------------- embed * sqrt(d) + positional encoding ----------------
  if (valid) {
    int tok = tokens[b * 1000 + t];
    const float4* ev = (const float4*)(emb + (size_t)tok * 64);
    if (petab != nullptr) {
      const float4* pv = (const float4*)(petab + (size_t)t * 64);
#define EMBQ(Q) { float4 v4 = ev[Q]; float4 p4 = pv[Q];                         \
      x[2*(Q)]   = packh2(fmaf(v4.x, 8.f, p4.x), fmaf(v4.y, 8.f, p4.y));        \
      x[2*(Q)+1] = packh2(fmaf(v4.z, 8.f, p4.z), fmaf(v4.w, 8.f, p4.w)); }
      RPT16(EMBQ)
#undef EMBQ
    } else {
      float fs = (float)t;
#define EMBT(Q) { float4 v4 = ev[Q];                                            \
      float d0 = exp2f(-0.4152410118609203f * (float)((4*(Q)) >> 1));           \
      float d1 = exp2f(-0.4152410118609203f * (float)((4*(Q)+2) >> 1));         \
      float pe0 = sinf(fs*d0), pe1 = cosf(fs*d0);                               \
      float pe2 = sinf(fs*d1), pe3 = cosf(fs*d1);                               \
      x[2*(Q)]   = packh2(fmaf(v4.x, 8.f, pe0), fmaf(v4.y, 8.f, pe1));          \
      x[2*(Q)+1] = packh2(fmaf(v4.z, 8.f, pe2), fmaf(v4.w, 8.f, pe3)); }
      RPT16(EMBT)
#undef EMBT
    }
  } else {
#define ZX(K) x[K] = 0u;
    RPT32(ZX)
#undef ZX
  }

  for (int l = 0; l < NL; l++) {
    const float* n1g = n1_g + l * 64;
    const float* n1b = n1_b + l * 64;
    const float* n2g = n2_g + l * 64;
    const float* n2b = n2_b + l * 64;
    const float* f1b = ff1_b + l * 64;
    const float* f2b = ff2_b + l * 64;
    const uint32_t* w1base = wpk1 + l * 2048;   // [dp][64]
    const uint32_t* w2base = wpk2 + l * 2048;   // [o][32]

    // ------- avg over sequence: two 32-channel half-butterflies (v[32] peak,
    // not v[64]) + cross-group shfl_xor(32) + LDS cross-wave combine -------
    float r0, r1;
    {
      float v[32];
      // 5-stage butterfly within 32-lane groups: lane ends holding channel
      // (lane&31) summed over its 32-lane group; final xor(32) adds groups.
#define BFH(MM, K) { bool up = (lane & (MM)) != 0;                              \
      float snd = up ? v[K] : v[(K)+(MM)];                                      \
      float kp  = up ? v[(K)+(MM)] : v[K];                                      \
      v[K] = kp + __shfl_xor(snd, (MM), 64); }
#define BF16h(K) BFH(16, K)
#define BF8h(K) BFH(8, K)
#define BF4h(K) BFH(4, K)
#define BF2h(K) BFH(2, K)

      // half 0: channels 0..31 = pairs x[0..15]
#define AVGL0(DP) { float2 a = valid ? unpackh2(x[DP]) : make_float2(0.f, 0.f); \
      v[2*(DP)] = a.x; v[2*(DP)+1] = a.y; }
      RPT16(AVGL0)
#undef AVGL0
      RPT16(BF16h)
      RPT8x(BF8h)
      RPT4x(BF4h)
      RPT2x(BF2h)
      BFH(1, 0)
      r0 = v[0] + __shfl_xor(v[0], 32, 64);

      // half 1: channels 32..63 = pairs x[16..31]
#define AVGL1(DP) { float2 a = valid ? unpackh2(x[(DP)+16]) : make_float2(0.f, 0.f); \
      v[2*(DP)] = a.x; v[2*(DP)+1] = a.y; }
      RPT16(AVGL1)
#undef AVGL1
      RPT16(BF16h)
      RPT8x(BF8h)
      RPT4x(BF4h)
      RPT2x(BF2h)
      BFH(1, 0)
      r1 = v[0] + __shfl_xor(v[0], 32, 64);
#undef BF2h
#undef BF4h
#undef BF8h
#undef BF16h
#undef BFH
    }
    __syncthreads();
    if (lane < 32) {
      redw[wv][lane] = r0;
      redw[wv][32 + lane] = r1;
    }
    __syncthreads();
    if (t < 64) {
      float s = 0.f;
      #pragma unroll
      for (int w = 0; w < 16; w++) s += redw[w][t];
      avgbuf[t] = s * 1e-3f;
    }
    __syncthreads();
    if (t < 64) {  // attn[o] = lin_b[o] + sum_d avg[d]*lin_w[o][d]
      const float* wr = lin_w + (size_t)(l * 64 + t) * 64;
      float a0 = lin_b[l * 64 + t], a1 = 0.f, a2 = 0.f, a3 = 0.f;
      #pragma unroll
      for (int d = 0; d < 64; d += 4) {
        a0 += avgbuf[d] * wr[d];
        a1 += avgbuf[d + 1] * wr[d + 1];
        a2 += avgbuf[d + 2] * wr[d + 2];
        a3 += avgbuf[d + 3] * wr[d + 3];
      }
      attnbuf[t] = (a0 + a1) + (a2 + a3);
    }
    __syncthreads();

    const float2* at2 = (const float2*)attnbuf;

    // ---------------- LN1 stats over v = x + attn ----------------
    float m0 = 0.f, m1 = 0.f, q0 = 0.f, q1 = 0.f;
#define LN1S(DP) { float2 xv = unpackh2(x[DP]); float2 at = at2[DP];            \
    float a0 = xv.x + at.x, a1 = xv.y + at.y;                                   \
    m0 += a0; m1 += a1; q0 = fmaf(a0, a0, q0); q1 = fmaf(a1, a1, q1); }
    RPT32(LN1S)
#undef LN1S
    float mu = (m0 + m1) * (1.0f / 64.0f);
    float var = (q0 + q1) * (1.0f / 64.0f) - mu * mu;
    float rs = rsqrtf(var + 1e-5f);

    // ---------------- LN1 normalize -> y (registers); x dead after ----------------
#define LN1N(DP) { float2 xv = unpackh2(x[DP]); float2 at = at2[DP];            \
    float a0 = xv.x + at.x, a1 = xv.y + at.y;                                   \
    float y0 = fmaf((a0 - mu) * rs, n1g[2*(DP)],   n1b[2*(DP)]);                \
    float y1 = fmaf((a1 - mu) * rs, n1g[2*(DP)+1], n1b[2*(DP)+1]);              \
    y[DP] = packh2(y0, y1); }
    RPT32(LN1N)
#undef LN1N

    // ---------------- mm1: h = relu(y @ W1^T + b1), two 32-output halves ----------------
    uint32_t hpk[32];
    {
      float acc[32];
      #pragma unroll
      for (int o = 0; o < 32; o++) acc[o] = f1b[o];
#define MM1D(DP) { uint32_t yv = y[DP]; const uint32_t* wr = w1base + (DP)*64;  \
      _Pragma("unroll") for (int o = 0; o < 32; o++)                            \
        acc[o] = fdot2h(yv, wr[o], acc[o]); }
      RPT32(MM1D)
#undef MM1D
      #pragma unroll
      for (int p = 0; p < 16; p++)
        hpk[p] = packh2(fmaxf(acc[2*p], 0.f), fmaxf(acc[2*p+1], 0.f));
    }
    {
      float acc[32];
      #pragma unroll
      for (int o = 0; o < 32; o++) acc[o] = f1b[32 + o];
#define MM1D(DP) { uint32_t yv = y[DP]; const uint32_t* wr = w1base + (DP)*64 + 32; \
      _Pragma("unroll") for (int o = 0; o < 32; o++)                            \
        acc[o] = fdot2h(yv, wr[o], acc[o]); }
      RPT32(MM1D)
#undef MM1D
      #pragma unroll
      for (int p = 0; p < 16; p++)
        hpk[16 + p] = packh2(fmaxf(acc[2*p], 0.f), fmaxf(acc[2*p+1], 0.f));
    }

    // ---------------- mm2 + residual (y) + LN2 stats; result back into y ----------------
    float mm0 = 0.f, mm1v = 0.f, qq0 = 0.f, qq1 = 0.f;
#define MM2O(OP) { const uint32_t* w0 = w2base + (OP)*64;                       \
    const uint32_t* w1p = w0 + 32;                                              \
    float a0 = f2b[2*(OP)], a1 = f2b[2*(OP)+1];                                 \
    float b0 = 0.f, b1v = 0.f;                                                  \
    _Pragma("unroll") for (int dhp = 0; dhp < 32; dhp += 2) {                   \
      a0  = fdot2h(hpk[dhp],     w0[dhp],      a0);                             \
      b0  = fdot2h(hpk[dhp + 1], w0[dhp + 1],  b0);                             \
      a1  = fdot2h(hpk[dhp],     w1p[dhp],     a1);                             \
      b1v = fdot2h(hpk[dhp + 1], w1p[dhp + 1], b1v);                            \
    }                                                                           \
    a0 += b0; a1 += b1v;                                                        \
    float2 yv2 = unpackh2(y[OP]);                                               \
    a0 += yv2.x; a1 += yv2.y;                                                   \
    mm0 += a0; mm1v += a1;                                                      \
    qq0 = fmaf(a0, a0, qq0); qq1 = fmaf(a1, a1, qq1);                           \
    y[OP] = packh2(a0, a1); }
    RPT32(MM2O)
#undef MM2O
    float mu2 = (mm0 + mm1v) * (1.0f / 64.0f);
    float var2 = (qq0 + qq1) * (1.0f / 64.0f) - mu2 * mu2;
    float rs2 = rsqrtf(var2 + 1e-5f);

    // ---------------- LN2 normalize -> x (next layer) ----------------
#define LN2N(DP) { float2 tv = unpackh2(y[DP]);                                 \
    float x0v = fmaf((tv.x - mu2) * rs2, n2g[2*(DP)],   n2b[2*(DP)]);           \
    float x1v = fmaf((tv.y - mu2) * rs2, n2g[2*(DP)+1], n2b[2*(DP)+1]);         \
    x[DP] = packh2(x0v, x1v); }
    RPT32(LN2N)
#undef LN2N
  }

  // ---------------- output projection [B,S,2] ----------------
  if (valid) {
    float a0 = out_b[0], a1 = out_b[1];
#define OUTD(DP) { float2 xv = unpackh2(x[DP]);                                 \
    a0 += xv.x * out_w[2*(DP)]      + xv.y * out_w[2*(DP)+1];                   \
    a1 += xv.x * out_w[64 + 2*(DP)] + xv.y * out_w[64 + 2*(DP)+1]; }
    RPT32(OUTD)
#undef OUTD
    *(float2*)(out + (size_t)(b * 1000 + t) * 2) = make_float2(a0, a1);
  }
}

extern "C" void kernel_launch(void* const* d_in, const int* in_sizes, int n_in,
                              void* d_out, int out_size, void* d_ws, size_t ws_size,
                              hipStream_t stream) {
  const int* tokens = (const int*)d_in[0];
  const float* emb = (const float*)d_in[1];
  const float* lin_w = (const float*)d_in[2];
  const float* lin_b = (const float*)d_in[3];
  const float* ff1_w = (const float*)d_in[4];
  const float* ff1_b = (const float*)d_in[5];
  const float* ff2_w = (const float*)d_in[6];
  const float* ff2_b = (const float*)d_in[7];
  const float* n1_g = (const float*)d_in[8];
  const float* n1_b = (const float*)d_in[9];
  const float* n2_g = (const float*)d_in[10];
  const float* n2_b = (const float*)d_in[11];
  const float* out_w = (const float*)d_in[12];
  const float* out_b = (const float*)d_in[13];
  float* out = (float*)d_out;

  uint32_t* wpk1 = (uint32_t*)d_ws;       // 32 KiB
  uint32_t* wpk2 = wpk1 + 4 * 32 * 64;    // 32 KiB
  float* petab = (float*)(wpk2 + 4 * 64 * 32);  // 250 KiB (1000*64 f32)
  const size_t need = 16384 * 4 + 64000 * 4;
  const bool use_pe = (ws_size >= need);
  float* pe_arg = use_pe ? petab : nullptr;

  int pack_threads = 16384 + (use_pe ? 64000 : 0);
  int pack_blocks = (pack_threads + 255) / 256;
  pack_weights_kernel<<<pack_blocks, 256, 0, stream>>>(ff1_w, ff2_w, wpk1, wpk2, pe_arg);
  aat_kernel<<<512, TPB, 0, stream>>>(tokens, emb, lin_w, lin_b, ff1_b, ff2_b,
                                      n1_g, n1_b, n2_g, n2_b, out_w, out_b,
                                      wpk1, wpk2, pe_arg, out);
}

// Round 7
// 636.580 us; speedup vs baseline: 1.1517x; 1.0075x over previous
//
#include <hip/hip_runtime.h>
#include <stdint.h>

#define TPB 1024
#define NL 4
#define XS 33  // row stride in u32: +1 pad makes row-wise AND column-wise LDS access conflict-free

typedef _Float16 half2v __attribute__((ext_vector_type(2)));

static __device__ __forceinline__ uint32_t packh2(float a, float b) {
  half2v h;
  h.x = (_Float16)a;
  h.y = (_Float16)b;
  return __builtin_bit_cast(uint32_t, h);
}
static __device__ __forceinline__ float2 unpackh2(uint32_t u) {
  half2v h = __builtin_bit_cast(half2v, u);
  return make_float2((float)h.x, (float)h.y);
}
static __device__ __forceinline__ float fdot2h(uint32_t a, uint32_t b, float c) {
#if __has_builtin(__builtin_amdgcn_fdot2)
  return __builtin_amdgcn_fdot2(__builtin_bit_cast(half2v, a),
                                __builtin_bit_cast(half2v, b), c, false);
#else
  half2v x = __builtin_bit_cast(half2v, a);
  half2v y = __builtin_bit_cast(half2v, b);
  return c + (float)x.x * (float)y.x + (float)x.y * (float)y.y;
#endif
}

// Pack ff1_w as wpk1[l][dp][o]  = half2(W1[o][2dp], W1[o][2dp+1])   (8192 u32)
// Pack ff2_w as wpk2[l][o][dhp] = half2(W2[o][2dhp], W2[o][2dhp+1]) (8192 u32)
// Also fill petab[s][d] = PE(s,d) for s<1000, d<64 (f32) when petab != nullptr.
__global__ void pack_weights_kernel(const float* __restrict__ ff1_w,
                                    const float* __restrict__ ff2_w,
                                    uint32_t* __restrict__ wpk1,
                                    uint32_t* __restrict__ wpk2,
                                    float* __restrict__ petab) {
  int idx = blockIdx.x * blockDim.x + threadIdx.x;
  if (idx < 8192) {
    int l = idx >> 11, dp = (idx >> 6) & 31, o = idx & 63;
    wpk1[idx] = packh2(ff1_w[(l * 64 + o) * 64 + 2 * dp],
                       ff1_w[(l * 64 + o) * 64 + 2 * dp + 1]);
  } else if (idx < 16384) {
    int j = idx - 8192;
    int l = j >> 11, o = (j >> 5) & 63, dhp = j & 31;
    wpk2[j] = packh2(ff2_w[(l * 64 + o) * 64 + 2 * dhp],
                     ff2_w[(l * 64 + o) * 64 + 2 * dhp + 1]);
  } else if (petab != nullptr && idx < 16384 + 64000) {
    int j = idx - 16384;
    int s = j >> 6, d = j & 63;
    // div_i = 10000^(-i/32), i = d>>1 ; log2(10000)/32 = 0.41524101186
    float div = exp2f(-0.4152410118609203f * (float)(d >> 1));
    float ang = (float)s * div;
    petab[j] = (d & 1) ? cosf(ang) : sinf(ang);
  }
}

// Thread-per-row, but the row state lives in LDS, not registers.
// Six rounds of evidence: per-thread arrays >32 elements of persistent state
// are demoted to scratch regardless of VGPR budget directives (R1: 256-reg
// budget, same spill; R5/R6: waves_per_eu pin ignored, VGPR stuck at 64).
// LDS X[1000][33] (132 KB) holds all rows; registers hold only the transient
// acc[32]/hpk[32] (the size class that promoted in every round, ~60 regs
// peak). The 141 KB LDS footprint forces 1 block/CU, aligning the backend's
// occupancy heuristic (4 waves/EU) with the register need instead of
// fighting it. Weights are wave-uniform global reads -> scalar loads (SGPR).
__global__ __launch_bounds__(TPB) void aat_kernel(
    const int* __restrict__ tokens, const float* __restrict__ emb,
    const float* __restrict__ lin_w, const float* __restrict__ lin_b,
    const float* __restrict__ ff1_b, const float* __restrict__ ff2_b,
    const float* __restrict__ n1_g, const float* __restrict__ n1_b,
    const float* __restrict__ n2_g, const float* __restrict__ n2_b,
    const float* __restrict__ out_w, const float* __restrict__ out_b,
    const uint32_t* __restrict__ wpk1, const uint32_t* __restrict__ wpk2,
    const float* __restrict__ petab, float* __restrict__ out) {
  __shared__ uint32_t X[1000 * XS];                 // 132000 B: rows, f16 pairs
  __shared__ float redbuf[32 * 64];                 // 8 KB: avg partials
  __shared__ float avgbuf[64];
  __shared__ __align__(8) float attnbuf[64];

  const int t = threadIdx.x;
  const int b = blockIdx.x;
  const bool valid = (t < 1000);
  const int base = t * XS;

  // ---------------- embed * sqrt(d) + positional encoding -> X ----------------
  if (valid) {
    int tok = tokens[b * 1000 + t];
    const float4* ev = (const float4*)(emb + (size_t)tok * 64);
    if (petab != nullptr) {
      const float4* pv = (const float4*)(petab + (size_t)t * 64);
      #pragma unroll
      for (int q = 0; q < 16; q++) {
        float4 v4 = ev[q];
        float4 p4 = pv[q];
        X[base + 2 * q] = packh2(fmaf(v4.x, 8.f, p4.x), fmaf(v4.y, 8.f, p4.y));
        X[base + 2 * q + 1] = packh2(fmaf(v4.z, 8.f, p4.z), fmaf(v4.w, 8.f, p4.w));
      }
    } else {
      float fs = (float)t;
      #pragma unroll
      for (int q = 0; q < 16; q++) {
        float4 v4 = ev[q];
        float d0 = exp2f(-0.4152410118609203f * (float)((4 * q) >> 1));
        float d1 = exp2f(-0.4152410118609203f * (float)((4 * q + 2) >> 1));
        float pe0 = sinf(fs * d0), pe1 = cosf(fs * d0);
        float pe2 = sinf(fs * d1), pe3 = cosf(fs * d1);
        X[base + 2 * q] = packh2(fmaf(v4.x, 8.f, pe0), fmaf(v4.y, 8.f, pe1));
        X[base + 2 * q + 1] = packh2(fmaf(v4.z, 8.f, pe2), fmaf(v4.w, 8.f, pe3));
      }
    }
  }
  __syncthreads();

  for (int l = 0; l < NL; l++) {
    const float* n1g = n1_g + l * 64;
    const float* n1b = n1_b + l * 64;
    const float* n2g = n2_g + l * 64;
    const float* n2b = n2_b + l * 64;
    const float* f1b = ff1_b + l * 64;
    const float* f2b = ff2_b + l * 64;
    const uint32_t* w1base = wpk1 + l * 2048;   // [dp][64]
    const uint32_t* w2base = wpk2 + l * 2048;   // [o][32]

    // ------- avg over sequence: column-parallel partials, no register arrays -------
    {
      int cp = t & 31, rg = t >> 5;     // channel-pair, row-group
      float s0 = 0.f, s1 = 0.f;
      for (int r = rg; r < 1000; r += 32) {   // bank = (r+cp)%32: 2 lanes/bank, free
        float2 v = unpackh2(X[r * XS + cp]);
        s0 += v.x;
        s1 += v.y;
      }
      redbuf[rg * 64 + 2 * cp] = s0;
      redbuf[rg * 64 + 2 * cp + 1] = s1;
    }
    __syncthreads();
    if (t < 64) {
      float s = 0.f;
      #pragma unroll
      for (int w = 0; w < 32; w++) s += redbuf[w * 64 + t];
      avgbuf[t] = s * 1e-3f;
    }
    __syncthreads();
    if (t < 64) {  // attn[o] = lin_b[o] + sum_d avg[d]*lin_w[o][d]
      const float* wr = lin_w + (size_t)(l * 64 + t) * 64;
      float a0 = lin_b[l * 64 + t], a1 = 0.f, a2 = 0.f, a3 = 0.f;
      #pragma unroll
      for (int d = 0; d < 64; d += 4) {
        a0 += avgbuf[d] * wr[d];
        a1 += avgbuf[d + 1] * wr[d + 1];
        a2 += avgbuf[d + 2] * wr[d + 2];
        a3 += avgbuf[d + 3] * wr[d + 3];
      }
      attnbuf[t] = (a0 + a1) + (a2 + a3);
    }
    __syncthreads();

    if (valid) {
      const float2* at2 = (const float2*)attnbuf;

      // ---- LN1 stats over v = x + attn (stream from LDS, no arrays) ----
      float m0 = 0.f, m1 = 0.f, q0 = 0.f, q1 = 0.f;
      for (int dp = 0; dp < 32; dp++) {
        float2 xv = unpackh2(X[base + dp]);
        float2 at = at2[dp];
        float a0 = xv.x + at.x, a1 = xv.y + at.y;
        m0 += a0;
        m1 += a1;
        q0 = fmaf(a0, a0, q0);
        q1 = fmaf(a1, a1, q1);
      }
      float mu = (m0 + m1) * (1.0f / 64.0f);
      float var = (q0 + q1) * (1.0f / 64.0f) - mu * mu;
      float rs = rsqrtf(var + 1e-5f);

      // ---- LN1 normalize: Y overwrites X (X dead after this) ----
      for (int dp = 0; dp < 32; dp++) {
        float2 xv = unpackh2(X[base + dp]);
        float2 at = at2[dp];
        float a0 = xv.x + at.x, a1 = xv.y + at.y;
        float y0 = fmaf((a0 - mu) * rs, n1g[2 * dp], n1b[2 * dp]);
        float y1 = fmaf((a1 - mu) * rs, n1g[2 * dp + 1], n1b[2 * dp + 1]);
        X[base + dp] = packh2(y0, y1);
      }

      // ---- mm1: h = relu(Y @ W1^T + b1), two 32-output halves ----
      uint32_t hpk[32];
      #pragma unroll
      for (int h = 0; h < 2; h++) {
        float acc[32];
        #pragma unroll
        for (int o = 0; o < 32; o++) acc[o] = f1b[32 * h + o];
        for (int dp = 0; dp < 32; dp++) {
          uint32_t y2 = X[base + dp];
          const uint32_t* wr = w1base + dp * 64 + 32 * h;   // wave-uniform -> s_load
          #pragma unroll
          for (int o = 0; o < 32; o++) acc[o] = fdot2h(y2, wr[o], acc[o]);
        }
        #pragma unroll
        for (int p = 0; p < 16; p++)
          hpk[16 * h + p] = packh2(fmaxf(acc[2 * p], 0.f), fmaxf(acc[2 * p + 1], 0.f));
      }

      // ---- mm2 + residual (Y in LDS) + LN2 stats; T overwrites Y in LDS ----
      float mm0 = 0.f, mm1v = 0.f, qq0 = 0.f, qq1 = 0.f;
      for (int op = 0; op < 32; op++) {
        const uint32_t* w0 = w2base + op * 64;              // wave-uniform -> s_load
        const uint32_t* w1p = w0 + 32;
        float a0 = f2b[2 * op], a1 = f2b[2 * op + 1];
        float b0 = 0.f, b1v = 0.f;
        #pragma unroll
        for (int dhp = 0; dhp < 32; dhp += 2) {
          a0 = fdot2h(hpk[dhp], w0[dhp], a0);
          b0 = fdot2h(hpk[dhp + 1], w0[dhp + 1], b0);
          a1 = fdot2h(hpk[dhp], w1p[dhp], a1);
          b1v = fdot2h(hpk[dhp + 1], w1p[dhp + 1], b1v);
        }
        a0 += b0;
        a1 += b1v;
        float2 yv = unpackh2(X[base + op]);
        a0 += yv.x;
        a1 += yv.y;
        mm0 += a0;
        mm1v += a1;
        qq0 = fmaf(a0, a0, qq0);
        qq1 = fmaf(a1, a1, qq1);
        X[base + op] = packh2(a0, a1);
      }
      float mu2 = (mm0 + mm1v) * (1.0f / 64.0f);
      float var2 = (qq0 + qq1) * (1.0f / 64.0f) - mu2 * mu2;
      float rs2 = rsqrtf(var2 + 1e-5f);

      // ---- LN2 normalize -> X (next layer) ----
      for (int dp = 0; dp < 32; dp++) {
        float2 tv = unpackh2(X[base + dp]);
        float x0v = fmaf((tv.x - mu2) * rs2, n2g[2 * dp], n2b[2 * dp]);
        float x1v = fmaf((tv.y - mu2) * rs2, n2g[2 * dp + 1], n2b[2 * dp + 1]);
        X[base + dp] = packh2(x0v, x1v);
      }
    }
    __syncthreads();   // LN2 writes visible before next layer's avg
  }

  // ---------------- output projection [B,S,2] ----------------
  if (valid) {
    float a0 = out_b[0], a1 = out_b[1];
    for (int dp = 0; dp < 32; dp++) {
      float2 xv = unpackh2(X[base + dp]);
      a0 += xv.x * out_w[2 * dp] + xv.y * out_w[2 * dp + 1];
      a1 += xv.x * out_w[64 + 2 * dp] + xv.y * out_w[64 + 2 * dp + 1];
    }
    *(float2*)(out + (size_t)(b * 1000 + t) * 2) = make_float2(a0, a1);
  }
}

extern "C" void kernel_launch(void* const* d_in, const int* in_sizes, int n_in,
                              void* d_out, int out_size, void* d_ws, size_t ws_size,
                              hipStream_t stream) {
  const int* tokens = (const int*)d_in[0];
  const float* emb = (const float*)d_in[1];
  const float* lin_w = (const float*)d_in[2];
  const float* lin_b = (const float*)d_in[3];
  const float* ff1_w = (const float*)d_in[4];
  const float* ff1_b = (const float*)d_in[5];
  const float* ff2_w = (const float*)d_in[6];
  const float* ff2_b = (const float*)d_in[7];
  const float* n1_g = (const float*)d_in[8];
  const float* n1_b = (const float*)d_in[9];
  const float* n2_g = (const float*)d_in[10];
  const float* n2_b = (const float*)d_in[11];
  const float* out_w = (const float*)d_in[12];
  const float* out_b = (const float*)d_in[13];
  float* out = (float*)d_out;

  uint32_t* wpk1 = (uint32_t*)d_ws;       // 32 KiB
  uint32_t* wpk2 = wpk1 + 4 * 32 * 64;    // 32 KiB
  float* petab = (float*)(wpk2 + 4 * 64 * 32);  // 250 KiB (1000*64 f32)
  const size_t need = 16384 * 4 + 64000 * 4;
  const bool use_pe = (ws_size >= need);
  float* pe_arg = use_pe ? petab : nullptr;

  int pack_threads = 16384 + (use_pe ? 64000 : 0);
  int pack_blocks = (pack_threads + 255) / 256;
  pack_weights_kernel<<<pack_blocks, 256, 0, stream>>>(ff1_w, ff2_w, wpk1, wpk2, pe_arg);
  aat_kernel<<<512, TPB, 0, stream>>>(tokens, emb, lin_w, lin_b, ff1_b, ff2_b,
                                      n1_g, n1_b, n2_g, n2_b, out_w, out_b,
                                      wpk1, wpk2, pe_arg, out);
}

// Round 8
// 339.520 us; speedup vs baseline: 2.1594x; 1.8749x over previous
//
#include <hip/hip_runtime.h>
#include <stdint.h>

#define TPB 1024
#define NL 4
#define XS 33      // u32 row stride (+1 pad: row & column access both conflict-free)
#define CH 128     // GEMM chunk rows
#define NCHUNK 8   // 1024 / CH

typedef _Float16 f16;
typedef _Float16 half2v __attribute__((ext_vector_type(2)));
typedef _Float16 f16x8 __attribute__((ext_vector_type(8)));
typedef float f32x4 __attribute__((ext_vector_type(4)));
typedef uint32_t u32x4 __attribute__((ext_vector_type(4)));

static __device__ __forceinline__ uint32_t packh2(float a, float b) {
  half2v h;
  h.x = (_Float16)a;
  h.y = (_Float16)b;
  return __builtin_bit_cast(uint32_t, h);
}
static __device__ __forceinline__ float2 unpackh2(uint32_t u) {
  half2v h = __builtin_bit_cast(half2v, u);
  return make_float2((float)h.x, (float)h.y);
}

// w1h/w2h: plain f16 copies of ff1_w/ff2_w in original [l][o][d] layout
// (B-fragment for MFMA = 16B contiguous in d -> one aligned dwordx4 load).
// petab[s][d] = PE(s,d) when petab != nullptr.
__global__ void pack_weights_kernel(const float* __restrict__ ff1_w,
                                    const float* __restrict__ ff2_w,
                                    f16* __restrict__ w1h,
                                    f16* __restrict__ w2h,
                                    float* __restrict__ petab) {
  int idx = blockIdx.x * blockDim.x + threadIdx.x;
  if (idx < 16384) {
    w1h[idx] = (f16)ff1_w[idx];
  } else if (idx < 32768) {
    w2h[idx - 16384] = (f16)ff2_w[idx - 16384];
  } else if (petab != nullptr && idx < 32768 + 64000) {
    int j = idx - 32768;
    int s = j >> 6, d = j & 63;
    // div_i = 10000^(-i/32), i = d>>1 ; log2(10000)/32 = 0.41524101186
    float div = exp2f(-0.4152410118609203f * (float)(d >> 1));
    float ang = (float)s * div;
    petab[j] = (d & 1) ? cosf(ang) : sinf(ang);
  }
}

// Thread-per-row for embed/avg/LN phases (R7 structure, spill-free, 0 bank
// conflicts); MFMA for the FF GEMMs (R7 PMC: MfmaUtil=0 while 4096 v_dot2
// per thread per layer = ~75% of VALU issue -- the dominant cost).
// X padded to 1024 rows (pads kept zero). GEMM chunked at 128 rows so the
// H buffer (16.9 KB, unioned with avg-phase redbuf) fits LDS: total 152.6 KB.
// Fragment layouts (m89/m92-verified): A/B lane&15=row/col, k=8*(lane>>4)+j
// consecutive; C/D col=lane&15, row=4*(lane>>4)+reg.
__global__ __launch_bounds__(TPB) void aat_kernel(
    const int* __restrict__ tokens, const float* __restrict__ emb,
    const float* __restrict__ lin_w, const float* __restrict__ lin_b,
    const float* __restrict__ ff1_b, const float* __restrict__ ff2_b,
    const float* __restrict__ n1_g, const float* __restrict__ n1_b,
    const float* __restrict__ n2_g, const float* __restrict__ n2_b,
    const float* __restrict__ out_w, const float* __restrict__ out_b,
    const f16* __restrict__ w1h, const f16* __restrict__ w2h,
    const float* __restrict__ petab, float* __restrict__ out) {
  __shared__ uint32_t X[1024 * XS];       // 135168 B: rows as f16 pairs
  __shared__ uint32_t Hbuf[CH * XS];      // 16896 B: H chunk / avg redbuf
  __shared__ float avgbuf[64];
  __shared__ __align__(8) float attnbuf[64];

  const int t = threadIdx.x;
  const int b = blockIdx.x;
  const int lane = t & 63;
  const int wv = t >> 6;                  // 0..15
  const bool valid = (t < 1000);
  const int base = t * XS;
  float* redbuf = (float*)Hbuf;           // [32][64] during avg phase
  f16* Xh = (f16*)X;                      // row stride 66 halfs
  f16* Hh = (f16*)Hbuf;

  // ---------------- embed * sqrt(d) + positional encoding -> X ----------------
  if (valid) {
    int tok = tokens[b * 1000 + t];
    const float4* ev = (const float4*)(emb + (size_t)tok * 64);
    if (petab != nullptr) {
      const float4* pv = (const float4*)(petab + (size_t)t * 64);
      #pragma unroll
      for (int q = 0; q < 16; q++) {
        float4 v4 = ev[q];
        float4 p4 = pv[q];
        X[base + 2 * q] = packh2(fmaf(v4.x, 8.f, p4.x), fmaf(v4.y, 8.f, p4.y));
        X[base + 2 * q + 1] = packh2(fmaf(v4.z, 8.f, p4.z), fmaf(v4.w, 8.f, p4.w));
      }
    } else {
      float fs = (float)t;
      #pragma unroll
      for (int q = 0; q < 16; q++) {
        float4 v4 = ev[q];
        float d0 = exp2f(-0.4152410118609203f * (float)((4 * q) >> 1));
        float d1 = exp2f(-0.4152410118609203f * (float)((4 * q + 2) >> 1));
        float pe0 = sinf(fs * d0), pe1 = cosf(fs * d0);
        float pe2 = sinf(fs * d1), pe3 = cosf(fs * d1);
        X[base + 2 * q] = packh2(fmaf(v4.x, 8.f, pe0), fmaf(v4.y, 8.f, pe1));
        X[base + 2 * q + 1] = packh2(fmaf(v4.z, 8.f, pe2), fmaf(v4.w, 8.f, pe3));
      }
    }
  } else {
    #pragma unroll
    for (int dp = 0; dp < 32; dp++) X[base + dp] = 0u;   // pad rows stay 0
  }
  __syncthreads();

  const int l15 = lane & 15;
  const int g4 = lane >> 4;               // 0..3
  const int nt = wv & 3;                  // this wave's output-column tile
  const int mt0 = wv >> 2;                // first row-tile (second = mt0+4)
  const int colo = nt * 16 + l15;         // this lane's output column

  for (int l = 0; l < NL; l++) {
    const float* n1g = n1_g + l * 64;
    const float* n1b = n1_b + l * 64;
    const float* n2g = n2_g + l * 64;
    const float* n2b = n2_b + l * 64;

    // ------- avg over sequence: column-parallel partials into redbuf -------
    {
      int cp = t & 31, rg = t >> 5;
      float s0 = 0.f, s1 = 0.f;
      for (int r = rg; r < 1000; r += 32) {
        float2 v = unpackh2(X[r * XS + cp]);
        s0 += v.x;
        s1 += v.y;
      }
      redbuf[rg * 64 + 2 * cp] = s0;
      redbuf[rg * 64 + 2 * cp + 1] = s1;
    }
    __syncthreads();
    if (t < 64) {
      float s = 0.f;
      #pragma unroll
      for (int w = 0; w < 32; w++) s += redbuf[w * 64 + t];
      avgbuf[t] = s * 1e-3f;
    }
    __syncthreads();
    if (t < 64) {  // attn[o] = lin_b[o] + sum_d avg[d]*lin_w[o][d]
      const float* wr = lin_w + (size_t)(l * 64 + t) * 64;
      float a0 = lin_b[l * 64 + t], a1 = 0.f, a2 = 0.f, a3 = 0.f;
      #pragma unroll
      for (int d = 0; d < 64; d += 4) {
        a0 += avgbuf[d] * wr[d];
        a1 += avgbuf[d + 1] * wr[d + 1];
        a2 += avgbuf[d + 2] * wr[d + 2];
        a3 += avgbuf[d + 3] * wr[d + 3];
      }
      attnbuf[t] = (a0 + a1) + (a2 + a3);
    }
    __syncthreads();

    // ---------------- LN1 (thread-per-row): Y overwrites X ----------------
    if (valid) {
      const float2* at2 = (const float2*)attnbuf;
      float m0 = 0.f, m1 = 0.f, q0 = 0.f, q1 = 0.f;
      for (int dp = 0; dp < 32; dp++) {
        float2 xv = unpackh2(X[base + dp]);
        float2 at = at2[dp];
        float a0 = xv.x + at.x, a1 = xv.y + at.y;
        m0 += a0;
        m1 += a1;
        q0 = fmaf(a0, a0, q0);
        q1 = fmaf(a1, a1, q1);
      }
      float mu = (m0 + m1) * (1.0f / 64.0f);
      float var = (q0 + q1) * (1.0f / 64.0f) - mu * mu;
      float rs = rsqrtf(var + 1e-5f);
      for (int dp = 0; dp < 32; dp++) {
        float2 xv = unpackh2(X[base + dp]);
        float2 at = at2[dp];
        float a0 = xv.x + at.x, a1 = xv.y + at.y;
        float y0 = fmaf((a0 - mu) * rs, n1g[2 * dp], n1b[2 * dp]);
        float y1 = fmaf((a1 - mu) * rs, n1g[2 * dp + 1], n1b[2 * dp + 1]);
        X[base + dp] = packh2(y0, y1);
      }
    }
    __syncthreads();

    // ---------------- FF via MFMA, chunked ----------------
    // This wave's B-fragments (W1/W2 row o = colo, k-halves) + biases.
    const f16* w1p = w1h + l * 4096 + colo * 64 + g4 * 8;
    f16x8 B1k0 = *(const f16x8*)(w1p);
    f16x8 B1k1 = *(const f16x8*)(w1p + 32);
    const f16* w2p = w2h + l * 4096 + colo * 64 + g4 * 8;
    f16x8 B2k0 = *(const f16x8*)(w2p);
    f16x8 B2k1 = *(const f16x8*)(w2p + 32);
    const float bias1 = ff1_b[l * 64 + colo];
    const float bias2 = ff2_b[l * 64 + colo];

    for (int c = 0; c < NCHUNK; c++) {
      // --- mm1 chunk: H = relu(Y @ W1^T + b1) -> Hh ---
      #pragma unroll
      for (int jj = 0; jj < 2; jj++) {
        const int mt = mt0 + 4 * jj;
        const int rowA = c * CH + mt * 16 + l15;
        f32x4 acc = {bias1, bias1, bias1, bias1};
        {
          int p = rowA * XS + g4 * 4;
          u32x4 aw = {X[p], X[p + 1], X[p + 2], X[p + 3]};
          acc = __builtin_amdgcn_mfma_f32_16x16x32_f16(
              __builtin_bit_cast(f16x8, aw), B1k0, acc, 0, 0, 0);
        }
        {
          int p = rowA * XS + 16 + g4 * 4;
          u32x4 aw = {X[p], X[p + 1], X[p + 2], X[p + 3]};
          acc = __builtin_amdgcn_mfma_f32_16x16x32_f16(
              __builtin_bit_cast(f16x8, aw), B1k1, acc, 0, 0, 0);
        }
        #pragma unroll
        for (int i = 0; i < 4; i++) {
          int r = mt * 16 + g4 * 4 + i;              // chunk-local row
          Hh[r * 66 + colo] = (f16)fmaxf(acc[i], 0.f);
        }
      }
      __syncthreads();
      // --- mm2 chunk: T = H @ W2^T + b2 + Y -> X (in place) ---
      #pragma unroll
      for (int jj = 0; jj < 2; jj++) {
        const int mt = mt0 + 4 * jj;
        f32x4 acc;
        #pragma unroll
        for (int i = 0; i < 4; i++) {
          int r = c * CH + mt * 16 + g4 * 4 + i;
          acc[i] = bias2 + (float)Xh[r * 66 + colo];  // residual Y
        }
        const int rowH = mt * 16 + l15;
        {
          int p = rowH * XS + g4 * 4;
          u32x4 aw = {Hbuf[p], Hbuf[p + 1], Hbuf[p + 2], Hbuf[p + 3]};
          acc = __builtin_amdgcn_mfma_f32_16x16x32_f16(
              __builtin_bit_cast(f16x8, aw), B2k0, acc, 0, 0, 0);
        }
        {
          int p = rowH * XS + 16 + g4 * 4;
          u32x4 aw = {Hbuf[p], Hbuf[p + 1], Hbuf[p + 2], Hbuf[p + 3]};
          acc = __builtin_amdgcn_mfma_f32_16x16x32_f16(
              __builtin_bit_cast(f16x8, aw), B2k1, acc, 0, 0, 0);
        }
        #pragma unroll
        for (int i = 0; i < 4; i++) {
          int r = c * CH + mt * 16 + g4 * 4 + i;
          Xh[r * 66 + colo] = (f16)acc[i];
        }
      }
      __syncthreads();
    }

    // ---------------- LN2 (thread-per-row) over T in X; pads re-zeroed ----------------
    if (valid) {
      float m0 = 0.f, m1 = 0.f, q0 = 0.f, q1 = 0.f;
      for (int dp = 0; dp < 32; dp++) {
        float2 tv = unpackh2(X[base + dp]);
        m0 += tv.x;
        m1 += tv.y;
        q0 = fmaf(tv.x, tv.x, q0);
        q1 = fmaf(tv.y, tv.y, q1);
      }
      float mu2 = (m0 + m1) * (1.0f / 64.0f);
      float var2 = (q0 + q1) * (1.0f / 64.0f) - mu2 * mu2;
      float rs2 = rsqrtf(var2 + 1e-5f);
      for (int dp = 0; dp < 32; dp++) {
        float2 tv = unpackh2(X[base + dp]);
        float x0v = fmaf((tv.x - mu2) * rs2, n2g[2 * dp], n2b[2 * dp]);
        float x1v = fmaf((tv.y - mu2) * rs2, n2g[2 * dp + 1], n2b[2 * dp + 1]);
        X[base + dp] = packh2(x0v, x1v);
      }
    } else {
      #pragma unroll
      for (int dp = 0; dp < 32; dp++) X[base + dp] = 0u;  // mm2 wrote junk to pads
    }
    __syncthreads();
  }

  // ---------------- output projection [B,S,2] ----------------
  if (valid) {
    float a0 = out_b[0], a1 = out_b[1];
    for (int dp = 0; dp < 32; dp++) {
      float2 xv = unpackh2(X[base + dp]);
      a0 += xv.x * out_w[2 * dp] + xv.y * out_w[2 * dp + 1];
      a1 += xv.x * out_w[64 + 2 * dp] + xv.y * out_w[64 + 2 * dp + 1];
    }
    *(float2*)(out + (size_t)(b * 1000 + t) * 2) = make_float2(a0, a1);
  }
}

extern "C" void kernel_launch(void* const* d_in, const int* in_sizes, int n_in,
                              void* d_out, int out_size, void* d_ws, size_t ws_size,
                              hipStream_t stream) {
  const int* tokens = (const int*)d_in[0];
  const float* emb = (const float*)d_in[1];
  const float* lin_w = (const float*)d_in[2];
  const float* lin_b = (const float*)d_in[3];
  const float* ff1_w = (const float*)d_in[4];
  const float* ff1_b = (const float*)d_in[5];
  const float* ff2_w = (const float*)d_in[6];
  const float* ff2_b = (const float*)d_in[7];
  const float* n1_g = (const float*)d_in[8];
  const float* n1_b = (const float*)d_in[9];
  const float* n2_g = (const float*)d_in[10];
  const float* n2_b = (const float*)d_in[11];
  const float* out_w = (const float*)d_in[12];
  const float* out_b = (const float*)d_in[13];
  float* out = (float*)d_out;

  f16* w1h = (f16*)d_ws;                       // 32 KiB
  f16* w2h = w1h + 16384;                      // 32 KiB
  float* petab = (float*)((char*)d_ws + 65536);  // 250 KiB (1000*64 f32)
  const size_t need = 65536 + 64000 * 4;
  const bool use_pe = (ws_size >= need);
  float* pe_arg = use_pe ? petab : nullptr;

  int pack_threads = 32768 + (use_pe ? 64000 : 0);
  int pack_blocks = (pack_threads + 255) / 256;
  pack_weights_kernel<<<pack_blocks, 256, 0, stream>>>(ff1_w, ff2_w, w1h, w2h, pe_arg);
  aat_kernel<<<512, TPB, 0, stream>>>(tokens, emb, lin_w, lin_b, ff1_b, ff2_b,
                                      n1_g, n1_b, n2_g, n2_b, out_w, out_b,
                                      w1h, w2h, pe_arg, out);
}